// Round 3
// baseline (1090.191 us; speedup 1.0000x reference)
//
#include <hip/hip_runtime.h>
#include <hip/hip_bf16.h>
#include <math.h>

#define EPSF 1e-5f

typedef __attribute__((ext_vector_type(8))) short bf16x8;
typedef __attribute__((ext_vector_type(4))) float f32x4;

__device__ __forceinline__ void gld16(const void* g, void* l) {
  __builtin_amdgcn_global_load_lds(
      (const __attribute__((address_space(1))) unsigned int*)g,
      (__attribute__((address_space(3))) unsigned int*)l, 16, 0, 0);
}

// ---------------- instance-norm stats over time axis ----------------
__global__ __launch_bounds__(256) void stats_kernel(
    const float* __restrict__ x, float* __restrict__ meanp,
    float* __restrict__ stdp, float* __restrict__ rstdp)
{
  int b = blockIdx.x;
  int tid = threadIdx.x;
  int c = tid & 31, ls = tid >> 5;
  const float* xb = x + (size_t)b * 16384;
  float s = 0.f, s2 = 0.f;
  for (int l = ls; l < 512; l += 8) {
    float v = xb[l * 32 + c];
    s += v; s2 += v * v;
  }
  __shared__ float sb[8][32];
  __shared__ float sb2[8][32];
  sb[ls][c] = s; sb2[ls][c] = s2;
  __syncthreads();
  if (ls == 0) {
#pragma unroll
    for (int i = 1; i < 8; ++i) { s += sb[i][c]; s2 += sb2[i][c]; }
    float m = s * (1.f / 512.f);
    float var = s2 * (1.f / 512.f) - m * m;
    float sd = sqrtf(var + EPSF);
    meanp[b * 32 + c] = m;
    stdp[b * 32 + c] = sd;
    rstdp[b * 32 + c] = 1.f / sd;
  }
}

// ---------------- Fourier-mask -> time-domain filter taps ----------------
// KF[nb][t] duplicated: KF[t] = KF[t+512] = k_nb[t&511]
__global__ __launch_bounds__(256) void kfilt_kernel(
    const float* __restrict__ mw, float* __restrict__ kf)
{
  int gid = blockIdx.x * 256 + threadIdx.x;
  int nb = gid >> 9, t = gid & 511;
  const float* m = mw + nb * 257;
  float s0 = 1.f / (1.f + expf(-m[0]));
  float sN = 1.f / (1.f + expf(-m[256]));
  float acc = s0 + ((t & 1) ? -sN : sN);
  for (int f = 1; f < 256; ++f) {
    float sig = 1.f / (1.f + expf(-m[f]));
    int tf = (t * f) & 511;
    acc += 2.f * sig * cosf(6.28318530717958647f * (float)tf * (1.f / 512.f));
  }
  float kv = acc * (1.f / 512.f);
  kf[nb * 1024 + t] = kv;
  kf[nb * 1024 + t + 512] = kv;
}

// ---------------- x -> normalized, transposed, hi/lo split: XNB[b*32+c][l' | l'+512] ----------------
__global__ __launch_bounds__(256) void xprep_kernel(
    const float* __restrict__ x, const float* __restrict__ meanp,
    const float* __restrict__ rstdp, __hip_bfloat16* __restrict__ xnb)
{
  __shared__ float xs[512 * 33];   // [l][c], stride 33 -> conflict-free phases
  int b = blockIdx.x, tid = threadIdx.x;
  const float* xb = x + (size_t)b * 16384;
#pragma unroll
  for (int i = 0; i < 16; ++i) {
    int idx4 = tid + i * 256;          // float4 index over 4096
    int l = idx4 >> 3, c0 = (idx4 & 7) * 4;
    float4 v = *(const float4*)(xb + idx4 * 4);
    xs[l * 33 + c0 + 0] = v.x;
    xs[l * 33 + c0 + 1] = v.y;
    xs[l * 33 + c0 + 2] = v.z;
    xs[l * 33 + c0 + 3] = v.w;
  }
  __syncthreads();
  for (int c = 0; c < 32; ++c) {
    float m = meanp[b * 32 + c];
    float r = rstdp[b * 32 + c];
    int l = tid * 2;
    float v0 = (xs[l * 33 + c] - m) * r;
    float v1 = (xs[(l + 1) * 33 + c] - m) * r;
    __hip_bfloat16 h0 = __float2bfloat16(v0);
    __hip_bfloat16 h1 = __float2bfloat16(v1);
    union { __hip_bfloat16 h[2]; unsigned int u; } H, L;
    H.h[0] = h0; H.h[1] = h1;
    L.h[0] = __float2bfloat16(v0 - __bfloat162float(h0));
    L.h[1] = __float2bfloat16(v1 - __bfloat162float(h1));
    unsigned int* dst =
        (unsigned int*)((unsigned short*)xnb + ((size_t)(b * 32 + c)) * 1024 + l);
    dst[0] = H.u;
    dst[256] = L.u;                      // +512 shorts
  }
}

// ---------------- circulant matrix build: CM[nb][l][l' | l'+512] bf16 hi|lo ----------------
__global__ __launch_bounds__(256) void cmat_kernel(
    const float* __restrict__ kf, __hip_bfloat16* __restrict__ cm)
{
  int t = threadIdx.x;
  int row = blockIdx.x * 4 + (t >> 6);   // 0..2047 over [nb][l]
  int nb = row >> 9, l = row & 511;
  int lp0 = (t & 63) * 8;
  union { __hip_bfloat16 h[8]; uint4 u; } H, L;
#pragma unroll
  for (int j = 0; j < 8; ++j) {
    float v = kf[nb * 1024 + 512 + l - (lp0 + j)];
    __hip_bfloat16 h = __float2bfloat16(v);
    H.h[j] = h;
    L.h[j] = __float2bfloat16(v - __bfloat162float(h));
  }
  unsigned short* dst = (unsigned short*)cm + (size_t)row * 1024 + lp0;
  *(uint4*)dst = H.u;
  *(uint4*)(dst + 512) = L.u;
}

// ---------------- fp32 -> bf16 hi/lo split: in [rows,K] -> out [rows,2K] ----------------
__global__ __launch_bounds__(256) void split_kernel(
    const float* __restrict__ in, __hip_bfloat16* __restrict__ out, int ks)
{
  int t = blockIdx.x * 256 + threadIdx.x;
  long long idx = (long long)t * 4;
  int K = 1 << ks;
  long long r = idx >> ks;
  int k = (int)(idx & (K - 1));
  float4 v = *(const float4*)(in + idx);
  float vv[4] = {v.x, v.y, v.z, v.w};
  union { __hip_bfloat16 h[4]; uint2 u; } H, L;
#pragma unroll
  for (int u = 0; u < 4; ++u) {
    H.h[u] = __float2bfloat16(vv[u]);
    L.h[u] = __float2bfloat16(vv[u] - __bfloat162float(H.h[u]));
  }
  unsigned short* ob = (unsigned short*)out + (r << (ks + 1)) + k;
  *(uint2*)ob = H.u;
  *(uint2*)(ob + K) = L.u;
}

// ---------------- split-bf16 MFMA GEMM: C = A*B^T over hi/lo segments ----------------
// 128x128 tile, 256 thr, BK=32, 16x16x32 bf16 MFMA.
// nseg==3: Ahi*Bhi + Ahi*Blo + Alo*Bhi; nseg==2: A hi-only.
// xihm==1: scatter hi-only output into enc1-A layout (conv path).
__global__ __launch_bounds__(256) void gemm_mfma(
    const __hip_bfloat16* __restrict__ A, int ldA, long long batchA,
    const __hip_bfloat16* __restrict__ B, int ldB, long long batchB,
    const float* __restrict__ bias, long long batchBias,
    float* __restrict__ Cf, int ldcf, long long batchCf,
    __hip_bfloat16* __restrict__ C2, int nhalf, long long batchC2,
    int M, int N, int K, int nseg, int relu, int xihm)
{
  __shared__ short sA[128 * 32];
  __shared__ short sB[128 * 32];
  int bz = blockIdx.z;
  const short* Ab = (const short*)A + (long long)bz * batchA;
  const short* Bb = (const short*)B + (long long)bz * batchB;
  int tid = threadIdx.x, wave = tid >> 6, lane = tid & 63;
  int bm = blockIdx.y << 7, bn = blockIdx.x << 7;
  int wrow = (wave >> 1) << 6, wcol = (wave & 1) << 6;

  int sr = lane >> 2;
  int qg = (lane & 3) ^ (sr & 3);
  int ar0 = wave << 5;

  f32x4 acc[4][4];
#pragma unroll
  for (int i = 0; i < 4; ++i)
#pragma unroll
    for (int j = 0; j < 4; ++j)
      acc[i][j] = (f32x4){0.f, 0.f, 0.f, 0.f};

  int frow = lane & 15;
  int fq = lane >> 4;
  int aoffs[4], boffs[4];
#pragma unroll
  for (int i = 0; i < 4; ++i) {
    int ra = wrow + 16 * i + frow;
    aoffs[i] = ra * 32 + ((fq ^ (ra & 3)) << 3);
    int rb = wcol + 16 * i + frow;
    boffs[i] = rb * 32 + ((fq ^ (rb & 3)) << 3);
  }

  for (int seg = 0; seg < nseg; ++seg) {
    int aoff = (seg == 2) ? K : 0;
    int boff = (seg == 1) ? K : 0;
    const short* Aseg = Ab + aoff + (long long)(bm + ar0 + sr) * ldA + qg * 8;
    const short* Bseg = Bb + boff + (long long)(bn + ar0 + sr) * ldB + qg * 8;
    for (int ko = 0; ko < K; ko += 32) {
      gld16(Aseg + ko, &sA[ar0 * 32]);
      gld16(Aseg + ko + 16 * ldA, &sA[(ar0 + 16) * 32]);
      gld16(Bseg + ko, &sB[ar0 * 32]);
      gld16(Bseg + ko + 16 * ldB, &sB[(ar0 + 16) * 32]);
      __syncthreads();
      bf16x8 af[4], bfr[4];
#pragma unroll
      for (int i = 0; i < 4; ++i) af[i] = *(const bf16x8*)&sA[aoffs[i]];
#pragma unroll
      for (int j = 0; j < 4; ++j) bfr[j] = *(const bf16x8*)&sB[boffs[j]];
#pragma unroll
      for (int i = 0; i < 4; ++i)
#pragma unroll
        for (int j = 0; j < 4; ++j)
          acc[i][j] = __builtin_amdgcn_mfma_f32_16x16x32_bf16(
              af[i], bfr[j], acc[i][j], 0, 0, 0);
      __syncthreads();
    }
  }

  if (xihm) {
    // m = l (0..511), n = b*32+c -> XIH row = b*8 + l/64, col = (l%64)*32 + c
    __hip_bfloat16* dst = C2 + (long long)bz * batchC2;
#pragma unroll
    for (int j = 0; j < 4; ++j) {
      int n = bn + wcol + 16 * j + frow;
      int bidx = n >> 5, c = n & 31;
#pragma unroll
      for (int i = 0; i < 4; ++i)
#pragma unroll
        for (int r = 0; r < 4; ++r) {
          int m = bm + wrow + 16 * i + fq * 4 + r;
          int row = bidx * 8 + (m >> 6);
          int col = (m & 63) * 32 + c;
          dst[(long long)row * 2048 + col] = __float2bfloat16(acc[i][j][r]);
        }
    }
    return;
  }

#pragma unroll
  for (int j = 0; j < 4; ++j) {
    int n = bn + wcol + 16 * j + frow;
    float bv = bias ? bias[(long long)bz * batchBias + n] : 0.f;
#pragma unroll
    for (int i = 0; i < 4; ++i) {
#pragma unroll
      for (int r = 0; r < 4; ++r) {
        int m = bm + wrow + 16 * i + fq * 4 + r;
        float v = acc[i][j][r] + bv;
        if (relu) v = fmaxf(v, 0.f);
        if (Cf) Cf[(long long)bz * batchCf + (long long)m * ldcf + n] = v;
        if (C2) {
          __hip_bfloat16 h = __float2bfloat16(v);
          __hip_bfloat16 l = __float2bfloat16(v - __bfloat162float(h));
          long long base = (long long)bz * batchC2 + (long long)m * (2 * nhalf);
          C2[base + n] = h;
          C2[base + nhalf + n] = l;
        }
      }
    }
  }
}

// ---------------- fp32 NT GEMM ----------------
__global__ __launch_bounds__(256) void gemm_nt(
    const float* __restrict__ A, int lda, long long batchA,
    const float* __restrict__ B, long long batchB,
    const float* __restrict__ bias, long long batchBias,
    const float* __restrict__ Add, int ldadd, long long batchAdd,
    float* __restrict__ C, int ldc, long long batchC,
    int M, int N, int K, int relu)
{
  int bz = blockIdx.z;
  A += (long long)bz * batchA;
  B += (long long)bz * batchB;
  C += (long long)bz * batchC;

  __shared__ float As[16][68];
  __shared__ float Bs[16][68];

  int tid = threadIdx.x;
  int lr = tid >> 2;
  int lk = (tid & 3) << 2;
  int tm = ((tid >> 4) & 15) << 2;
  int tn = (tid & 15) << 2;
  int bm = blockIdx.y << 6;
  int bn = blockIdx.x << 6;

  const float* Ap = A + (long long)(bm + lr) * lda + lk;
  const float* Bp = B + (long long)(bn + lr) * K + lk;

  float acc[4][4] = {};

  for (int kb = 0; kb < K; kb += 16) {
    float4 av = *(const float4*)(Ap + kb);
    float4 bv = *(const float4*)(Bp + kb);
    As[lk + 0][lr] = av.x; As[lk + 1][lr] = av.y;
    As[lk + 2][lr] = av.z; As[lk + 3][lr] = av.w;
    Bs[lk + 0][lr] = bv.x; Bs[lk + 1][lr] = bv.y;
    Bs[lk + 2][lr] = bv.z; Bs[lk + 3][lr] = bv.w;
    __syncthreads();
#pragma unroll
    for (int k = 0; k < 16; ++k) {
      float4 a4 = *(const float4*)&As[k][tm];
      float4 b4 = *(const float4*)&Bs[k][tn];
      const float* a = (const float*)&a4;
      const float* bq = (const float*)&b4;
#pragma unroll
      for (int i = 0; i < 4; ++i)
#pragma unroll
        for (int j = 0; j < 4; ++j)
          acc[i][j] = fmaf(a[i], bq[j], acc[i][j]);
    }
    __syncthreads();
  }

  float4 bb4 = make_float4(0.f, 0.f, 0.f, 0.f);
  if (bias) bb4 = *(const float4*)(bias + (long long)bz * batchBias + bn + tn);
  const float* addp = Add ? Add + (long long)bz * batchAdd : nullptr;
#pragma unroll
  for (int i = 0; i < 4; ++i) {
    int m = bm + tm + i;
    float4 o = make_float4(acc[i][0] + bb4.x, acc[i][1] + bb4.y,
                           acc[i][2] + bb4.z, acc[i][3] + bb4.w);
    if (addp) {
      float4 ad = *(const float4*)(addp + (long long)m * ldadd + bn + tn);
      o.x += ad.x; o.y += ad.y; o.z += ad.z; o.w += ad.w;
    }
    if (relu) {
      o.x = fmaxf(o.x, 0.f); o.y = fmaxf(o.y, 0.f);
      o.z = fmaxf(o.z, 0.f); o.w = fmaxf(o.w, 0.f);
    }
    *(float4*)(C + (long long)m * ldc + bn + tn) = o;
  }
}

// ---------------- recurrence prep: Vcat[j6]=W, Vcat[j7]=I, Vp[0:512]=W ----------------
__global__ __launch_bounds__(256) void rec_init_kernel(
    const float* __restrict__ whh, float* __restrict__ vcat, float* __restrict__ vp)
{
  int idx = blockIdx.x * 256 + threadIdx.x;      // 262144 float4s
  int nb = idx >> 16;
  int rem = idx & 65535;
  int i = rem >> 7;
  int j0 = (rem & 127) * 4;
  float4 w4 = *(const float4*)(whh + (size_t)nb * 262144 + i * 512 + j0);
  float* vb = vcat + (size_t)nb * 2097152 + (size_t)i * 4096;
  *(float4*)(vb + 3072 + j0) = w4;               // j=6 slice: V1 = W
  float4 id = make_float4(i == j0, i == j0 + 1, i == j0 + 2, i == j0 + 3);
  *(float4*)(vb + 3584 + j0) = id;               // j=7 slice: V0 = I
  *(float4*)(vp + (size_t)nb * 1048576 + i * 512 + j0) = w4;  // Vp rows 0..511 = V1
}

// ---------------- 64x64 tiled transpose: WT[nb] = whh[nb]^T ----------------
__global__ __launch_bounds__(256) void transpose_kernel(
    const float* __restrict__ w, float* __restrict__ wt)
{
  __shared__ float ts[64][65];
  int bx = blockIdx.x, by = blockIdx.y, nb = blockIdx.z;
  int t = threadIdx.x;
  int tr = t >> 4, c0 = (t & 15) * 4;
  const float* wb = w + (size_t)nb * 262144;
#pragma unroll
  for (int k = 0; k < 4; ++k) {
    int r = tr + k * 16;
    float4 v = *(const float4*)(wb + (size_t)(by * 64 + r) * 512 + bx * 64 + c0);
    ts[r][c0 + 0] = v.x; ts[r][c0 + 1] = v.y;
    ts[r][c0 + 2] = v.z; ts[r][c0 + 3] = v.w;
  }
  __syncthreads();
  float* ob = wt + (size_t)nb * 262144;
#pragma unroll
  for (int k = 0; k < 4; ++k) {
    int r = tr + k * 16;
    float4 v = make_float4(ts[c0][r], ts[c0 + 1][r], ts[c0 + 2][r], ts[c0 + 3][r]);
    *(float4*)(ob + (size_t)(bx * 64 + r) * 512 + by * 64 + c0) = v;
  }
}

// ---------------- copy V2,V3,V4 (Vp rows) into Vcat j5,j4,j3 slices ----------------
__global__ __launch_bounds__(256) void vcopy_kernel(
    const float* __restrict__ vp, float* __restrict__ vcat)
{
  int idx = blockIdx.x * 256 + threadIdx.x;      // 786432 float4s
  int s = idx >> 18;                             // 0..2 -> V2,V3,V4
  int rem = idx & 262143;
  int nb = rem >> 16;
  int rem2 = rem & 65535;
  int i = rem2 >> 7;
  int j0 = (rem2 & 127) * 4;
  float4 v = *(const float4*)(vp + (size_t)nb * 1048576 +
                              (size_t)((s + 1) * 512 + i) * 512 + j0);
  *(float4*)(vcat + (size_t)nb * 2097152 + (size_t)i * 4096 + (5 - s) * 512 + j0) = v;
}

// ---------------- LayerNorm over 512, writes bf16 hi/lo [row, 1024] ----------------
__global__ __launch_bounds__(256) void ln_kernel(
    const float* __restrict__ p, const float* __restrict__ g,
    const float* __restrict__ bb, __hip_bfloat16* __restrict__ p2)
{
  int row = blockIdx.x;              // NB*B*4 = 4096
  int nb = row >> 10;
  const float* pr = p + (size_t)row * 512;
  int tid = threadIdx.x;
  float v0 = pr[tid], v1 = pr[tid + 256];
  float s = v0 + v1, s2 = v0 * v0 + v1 * v1;
#pragma unroll
  for (int o = 32; o > 0; o >>= 1) {
    s += __shfl_down(s, o);
    s2 += __shfl_down(s2, o);
  }
  __shared__ float rs[4];
  __shared__ float rs2[4];
  int w = tid >> 6;
  if ((tid & 63) == 0) { rs[w] = s; rs2[w] = s2; }
  __syncthreads();
  s = rs[0] + rs[1] + rs[2] + rs[3];
  s2 = rs2[0] + rs2[1] + rs2[2] + rs2[3];
  float mval = s * (1.f / 512.f);
  float var = s2 * (1.f / 512.f) - mval * mval;
  float r = 1.f / sqrtf(var + EPSF);
  const float* gn = g + nb * 512;
  const float* bn = bb + nb * 512;
  float y0 = (v0 - mval) * r * gn[tid] + bn[tid];
  float y1 = (v1 - mval) * r * gn[tid + 256] + bn[tid + 256];
  __hip_bfloat16* o2 = p2 + (size_t)nb * 1048576 + (size_t)(row & 1023) * 1024;
  __hip_bfloat16 h0 = __float2bfloat16(y0);
  __hip_bfloat16 h1 = __float2bfloat16(y1);
  o2[tid] = h0;
  o2[tid + 256] = h1;
  o2[512 + tid] = __float2bfloat16(y0 - __bfloat162float(h0));
  o2[768 + tid] = __float2bfloat16(y1 - __bfloat162float(h1));
}

// ---------------- final: out = (sum_nb deco) * std + mean ----------------
__global__ __launch_bounds__(256) void final_kernel(
    const float* __restrict__ deco, const float* __restrict__ meanp,
    const float* __restrict__ stdp, float* __restrict__ out)
{
  int t = blockIdx.x * 256 + threadIdx.x;
  int b = t >> 11;
  int r = t & 2047;
  int p = (r >> 3) & 63;
  int cq = r & 7;
  size_t base = ((size_t)(b * 4 + (r >> 9))) * 2048 + p * 32 + cq * 4;
  const size_t nbs = 1024ull * 2048ull;
  float4 a0 = *(const float4*)(deco + base);
  float4 a1 = *(const float4*)(deco + nbs + base);
  float4 a2 = *(const float4*)(deco + 2 * nbs + base);
  float4 a3 = *(const float4*)(deco + 3 * nbs + base);
  float4 m4 = *(const float4*)(meanp + b * 32 + cq * 4);
  float4 s4 = *(const float4*)(stdp + b * 32 + cq * 4);
  float4 o;
  o.x = (a0.x + a1.x + a2.x + a3.x) * s4.x + m4.x;
  o.y = (a0.y + a1.y + a2.y + a3.y) * s4.y + m4.y;
  o.z = (a0.z + a1.z + a2.z + a3.z) * s4.z + m4.z;
  o.w = (a0.w + a1.w + a2.w + a3.w) * s4.w + m4.w;
  *(float4*)(out + (size_t)t * 4) = o;
}

extern "C" void kernel_launch(void* const* d_in, const int* in_sizes, int n_in,
                              void* d_out, int out_size, void* d_ws, size_t ws_size,
                              hipStream_t stream) {
  const float* x_enc  = (const float*)d_in[0];
  const float* mask_w = (const float*)d_in[4];
  const float* enc_w1 = (const float*)d_in[5];
  const float* enc_b1 = (const float*)d_in[6];
  const float* enc_w2 = (const float*)d_in[7];
  const float* enc_b2 = (const float*)d_in[8];
  const float* wxh    = (const float*)d_in[9];
  const float* whh    = (const float*)d_in[10];
  const float* ln_g   = (const float*)d_in[11];
  const float* ln_b   = (const float*)d_in[12];
  const float* dec_w1 = (const float*)d_in[13];
  const float* dec_b1 = (const float*)d_in[14];
  const float* dec_w2 = (const float*)d_in[15];
  const float* dec_b2 = (const float*)d_in[16];
  float* out = (float*)d_out;

  // ---- workspace layout; peak 96 MiB + 128 KiB head ----
  char* W = (char*)d_ws;
  float* MEAN = (float*)(W);
  float* STD  = (float*)(W + 32768);
  float* RSTD = (float*)(W + 65536);
  float* KF   = (float*)(W + 98304);
  char* B0 = W + 131072;
  // phase 1 (conv + enc1)
  __hip_bfloat16* XIH   = (__hip_bfloat16*)(B0);               // [0,32) MB
  __hip_bfloat16* XNB   = (__hip_bfloat16*)(B0 + 33554432);    // [32,48)
  __hip_bfloat16* CM    = (__hip_bfloat16*)(B0 + 50331648);    // [48,52)
  __hip_bfloat16* WW    = (__hip_bfloat16*)(B0 + 33554432);    // [32,64) after conv
  __hip_bfloat16* ENCB2 = (__hip_bfloat16*)(B0 + 67108864);    // [64,96)
  // phase 2 (enc2 / xp)
  __hip_bfloat16* EW2    = (__hip_bfloat16*)(B0);              // [0,8)
  __hip_bfloat16* WXH2   = (__hip_bfloat16*)(B0 + 8388608);    // [8,12)
  __hip_bfloat16* DW1    = (__hip_bfloat16*)(B0 + 12582912);   // [12,20)
  __hip_bfloat16* PREDS2 = (__hip_bfloat16*)(B0 + 20971520);   // [20,28)
  __hip_bfloat16* ENC22  = (__hip_bfloat16*)(B0 + 33554432);   // [32,48)
  float* XP    = (float*)(B0 + 67108864);                      // [64,80)
  // phase 3 (recurrence via powers)
  float* WT    = (float*)(B0);                                 // [0,4)   after enc2
  float* H7    = (float*)(B0 + 29360128);                      // [28,30)
  float* VCAT  = (float*)(B0 + 33554432);                      // [32,64) after xp
  float* VP    = (float*)(B0 + 83886080);                      // [80,96) after enc2
  float* PREDS = (float*)(B0 + 50331648);                      // [48,56) after h7
  // phase 4 (decoder)
  __hip_bfloat16* DW2   = (__hip_bfloat16*)(B0 + 33554432);    // [32,64) after ln
  __hip_bfloat16* DBUF2 = (__hip_bfloat16*)(B0 + 67108864);    // [64,80) after rec
  float* DECO  = (float*)(B0);                                 // [0,32)  at dec2

  stats_kernel<<<256, 256, 0, stream>>>(x_enc, MEAN, STD, RSTD);
  kfilt_kernel<<<8, 256, 0, stream>>>(mask_w, KF);
  xprep_kernel<<<256, 256, 0, stream>>>(x_enc, MEAN, RSTD, XNB);
  cmat_kernel<<<512, 256, 0, stream>>>(KF, CM);

  // conv as MFMA GEMM: per nb, [512,512]circ @ [8192,512]^T -> XIH scatter (hi only)
  gemm_mfma<<<dim3(64, 4, 4), 256, 0, stream>>>(
      CM, 1024, 524288LL, XNB, 1024, 0LL, nullptr, 0LL,
      nullptr, 0, 0LL, XIH, 0, 4194304LL, 512, 8192, 512, 3, 0, 1);

  // enc1: M=2048 N=1024 K=2048, A hi-only (nseg=2), relu, split-out
  split_kernel<<<8192, 256, 0, stream>>>(enc_w1, WW, 11);
  gemm_mfma<<<dim3(8, 16, 4), 256, 0, stream>>>(
      XIH, 2048, 4194304LL, WW, 4096, 4194304LL, enc_b1, 1024LL,
      nullptr, 0, 0LL, ENCB2, 1024, 4194304LL, 2048, 1024, 2048, 2, 1, 0);

  split_kernel<<<2048, 256, 0, stream>>>(enc_w2, EW2, 10);
  split_kernel<<<1024, 256, 0, stream>>>(wxh, WXH2, 9);
  split_kernel<<<2048, 256, 0, stream>>>(dec_w1, DW1, 9);

  // enc2: M=2048 N=512 K=1024, nseg=3, split-out
  gemm_mfma<<<dim3(4, 16, 4), 256, 0, stream>>>(
      ENCB2, 2048, 4194304LL, EW2, 2048, 1048576LL, enc_b2, 512LL,
      nullptr, 0, 0LL, ENC22, 512, 2097152LL, 2048, 512, 1024, 3, 0, 0);
  // xp = enc2 @ wxh^T: fp32 out  [nb][2048][512] == [nb][256][4096]
  gemm_mfma<<<dim3(4, 16, 4), 256, 0, stream>>>(
      ENC22, 1024, 2097152LL, WXH2, 1024, 524288LL, nullptr, 0LL,
      XP, 512, 1048576LL, nullptr, 0, 0LL, 2048, 512, 512, 3, 0, 0);

  // ---- recurrence via matrix powers ----
  rec_init_kernel<<<1024, 256, 0, stream>>>(whh, VCAT, VP);
  transpose_kernel<<<dim3(8, 8, 4), 256, 0, stream>>>(whh, WT);
  // chain: V2..V4 into VP rows, V5..V7 into VCAT j2,j1,j0 slices
  gemm_nt<<<dim3(8, 8, 4), 256, 0, stream>>>(          // V2 = W @ W
      whh, 512, 262144LL, WT, 262144LL, nullptr, 0LL, nullptr, 0, 0LL,
      VP + 262144, 512, 1048576LL, 512, 512, 512, 0);
  gemm_nt<<<dim3(8, 8, 4), 256, 0, stream>>>(          // V3 = V2 @ W
      VP + 262144, 512, 1048576LL, WT, 262144LL, nullptr, 0LL, nullptr, 0, 0LL,
      VP + 524288, 512, 1048576LL, 512, 512, 512, 0);
  gemm_nt<<<dim3(8, 8, 4), 256, 0, stream>>>(          // V4 = V3 @ W
      VP + 524288, 512, 1048576LL, WT, 262144LL, nullptr, 0LL, nullptr, 0, 0LL,
      VP + 786432, 512, 1048576LL, 512, 512, 512, 0);
  gemm_nt<<<dim3(8, 8, 4), 256, 0, stream>>>(          // V5 -> VCAT j=2
      VP + 786432, 512, 1048576LL, WT, 262144LL, nullptr, 0LL, nullptr, 0, 0LL,
      VCAT + 1024, 4096, 2097152LL, 512, 512, 512, 0);
  gemm_nt<<<dim3(8, 8, 4), 256, 0, stream>>>(          // V6 -> VCAT j=1
      VCAT + 1024, 4096, 2097152LL, WT, 262144LL, nullptr, 0LL, nullptr, 0, 0LL,
      VCAT + 512, 4096, 2097152LL, 512, 512, 512, 0);
  gemm_nt<<<dim3(8, 8, 4), 256, 0, stream>>>(          // V7 -> VCAT j=0
      VCAT + 512, 4096, 2097152LL, WT, 262144LL, nullptr, 0LL, nullptr, 0, 0LL,
      VCAT, 4096, 2097152LL, 512, 512, 512, 0);
  vcopy_kernel<<<3072, 256, 0, stream>>>(VP, VCAT);    // V2,V3,V4 -> VCAT j5,j4,j3

  // h7 = [xp_0..xp_7] @ Vcat^T : M=256 N=512 K=4096
  gemm_nt<<<dim3(8, 4, 4), 256, 0, stream>>>(
      XP, 4096, 1048576LL, VCAT, 2097152LL, nullptr, 0LL, nullptr, 0, 0LL,
      H7, 512, 131072LL, 256, 512, 4096, 0);
  // preds = h7 @ [V1;V2;V3;V4]^T : M=256 N=2048 K=512 -> PREDS rows b*4+s
  gemm_nt<<<dim3(32, 4, 4), 256, 0, stream>>>(
      H7, 512, 131072LL, VP, 1048576LL, nullptr, 0LL, nullptr, 0, 0LL,
      PREDS, 2048, 524288LL, 256, 2048, 512, 0);

  ln_kernel<<<4096, 256, 0, stream>>>(PREDS, ln_g, ln_b, PREDS2);

  split_kernel<<<8192, 256, 0, stream>>>(dec_w2, DW2, 10);
  // dec1: M=1024 N=1024 K=512, nseg=3, relu, split-out
  gemm_mfma<<<dim3(8, 8, 4), 256, 0, stream>>>(
      PREDS2, 1024, 1048576LL, DW1, 1024, 1048576LL, dec_b1, 1024LL,
      nullptr, 0, 0LL, DBUF2, 1024, 2097152LL, 1024, 1024, 512, 3, 1, 0);
  // dec2: M=1024 N=2048 K=1024, nseg=3, fp32 out
  gemm_mfma<<<dim3(16, 8, 4), 256, 0, stream>>>(
      DBUF2, 2048, 2097152LL, DW2, 2048, 4194304LL, dec_b2, 2048LL,
      DECO, 2048, 2097152LL, nullptr, 0, 0LL, 1024, 2048, 1024, 3, 0, 0);

  final_kernel<<<2048, 256, 0, stream>>>(DECO, MEAN, STD, out);
}

// Round 5
// 969.477 us; speedup vs baseline: 1.1245x; 1.1245x over previous
//
#include <hip/hip_runtime.h>
#include <hip/hip_bf16.h>
#include <math.h>

#define EPSF 1e-5f

typedef __attribute__((ext_vector_type(8))) short bf16x8;
typedef __attribute__((ext_vector_type(4))) float f32x4;

__device__ __forceinline__ void gld16(const void* g, void* l) {
  __builtin_amdgcn_global_load_lds(
      (const __attribute__((address_space(1))) unsigned int*)g,
      (__attribute__((address_space(3))) unsigned int*)l, 16, 0, 0);
}

// ---------------- instance-norm stats over time axis ----------------
__global__ __launch_bounds__(256) void stats_kernel(
    const float* __restrict__ x, float* __restrict__ meanp,
    float* __restrict__ stdp, float* __restrict__ rstdp)
{
  int b = blockIdx.x;
  int tid = threadIdx.x;
  int c = tid & 31, ls = tid >> 5;
  const float* xb = x + (size_t)b * 16384;
  float s = 0.f, s2 = 0.f;
  for (int l = ls; l < 512; l += 8) {
    float v = xb[l * 32 + c];
    s += v; s2 += v * v;
  }
  __shared__ float sb[8][32];
  __shared__ float sb2[8][32];
  sb[ls][c] = s; sb2[ls][c] = s2;
  __syncthreads();
  if (ls == 0) {
#pragma unroll
    for (int i = 1; i < 8; ++i) { s += sb[i][c]; s2 += sb2[i][c]; }
    float m = s * (1.f / 512.f);
    float var = s2 * (1.f / 512.f) - m * m;
    float sd = sqrtf(var + EPSF);
    meanp[b * 32 + c] = m;
    stdp[b * 32 + c] = sd;
    rstdp[b * 32 + c] = 1.f / sd;
  }
}

// ---------------- Fourier-mask -> time-domain filter taps (duplicated) ----------------
__global__ __launch_bounds__(256) void kfilt_kernel(
    const float* __restrict__ mw, float* __restrict__ kf)
{
  int gid = blockIdx.x * 256 + threadIdx.x;
  int nb = gid >> 9, t = gid & 511;
  const float* m = mw + nb * 257;
  float s0 = 1.f / (1.f + expf(-m[0]));
  float sN = 1.f / (1.f + expf(-m[256]));
  float acc = s0 + ((t & 1) ? -sN : sN);
  for (int f = 1; f < 256; ++f) {
    float sig = 1.f / (1.f + expf(-m[f]));
    int tf = (t * f) & 511;
    acc += 2.f * sig * cosf(6.28318530717958647f * (float)tf * (1.f / 512.f));
  }
  float kv = acc * (1.f / 512.f);
  kf[nb * 1024 + t] = kv;
  kf[nb * 1024 + t + 512] = kv;
}

// ---------------- x -> normalized, transposed, hi/lo split: XNB[b*32+c][l' | l'+512] ----------------
__global__ __launch_bounds__(256) void xprep_kernel(
    const float* __restrict__ x, const float* __restrict__ meanp,
    const float* __restrict__ rstdp, __hip_bfloat16* __restrict__ xnb)
{
  __shared__ float xs[512 * 33];
  int b = blockIdx.x, tid = threadIdx.x;
  const float* xb = x + (size_t)b * 16384;
#pragma unroll
  for (int i = 0; i < 16; ++i) {
    int idx4 = tid + i * 256;
    int l = idx4 >> 3, c0 = (idx4 & 7) * 4;
    float4 v = *(const float4*)(xb + idx4 * 4);
    xs[l * 33 + c0 + 0] = v.x;
    xs[l * 33 + c0 + 1] = v.y;
    xs[l * 33 + c0 + 2] = v.z;
    xs[l * 33 + c0 + 3] = v.w;
  }
  __syncthreads();
  for (int c = 0; c < 32; ++c) {
    float m = meanp[b * 32 + c];
    float r = rstdp[b * 32 + c];
    int l = tid * 2;
    float v0 = (xs[l * 33 + c] - m) * r;
    float v1 = (xs[(l + 1) * 33 + c] - m) * r;
    __hip_bfloat16 h0 = __float2bfloat16(v0);
    __hip_bfloat16 h1 = __float2bfloat16(v1);
    union { __hip_bfloat16 h[2]; unsigned int u; } H, L;
    H.h[0] = h0; H.h[1] = h1;
    L.h[0] = __float2bfloat16(v0 - __bfloat162float(h0));
    L.h[1] = __float2bfloat16(v1 - __bfloat162float(h1));
    unsigned int* dst =
        (unsigned int*)((unsigned short*)xnb + ((size_t)(b * 32 + c)) * 1024 + l);
    dst[0] = H.u;
    dst[256] = L.u;
  }
}

// ---------------- circulant matrix build: CM[nb][l][l' | l'+512] bf16 hi|lo ----------------
__global__ __launch_bounds__(256) void cmat_kernel(
    const float* __restrict__ kf, __hip_bfloat16* __restrict__ cm)
{
  int t = threadIdx.x;
  int row = blockIdx.x * 4 + (t >> 6);
  int nb = row >> 9, l = row & 511;
  int lp0 = (t & 63) * 8;
  union { __hip_bfloat16 h[8]; uint4 u; } H, L;
#pragma unroll
  for (int j = 0; j < 8; ++j) {
    float v = kf[nb * 1024 + 512 + l - (lp0 + j)];
    __hip_bfloat16 h = __float2bfloat16(v);
    H.h[j] = h;
    L.h[j] = __float2bfloat16(v - __bfloat162float(h));
  }
  unsigned short* dst = (unsigned short*)cm + (size_t)row * 1024 + lp0;
  *(uint4*)dst = H.u;
  *(uint4*)(dst + 512) = L.u;
}

// ---------------- fp32 -> bf16 hi/lo split: in [rows,K] -> out [rows,2K] ----------------
__global__ __launch_bounds__(256) void split_kernel(
    const float* __restrict__ in, __hip_bfloat16* __restrict__ out, int ks)
{
  int t = blockIdx.x * 256 + threadIdx.x;
  long long idx = (long long)t * 4;
  int K = 1 << ks;
  long long r = idx >> ks;
  int k = (int)(idx & (K - 1));
  float4 v = *(const float4*)(in + idx);
  float vv[4] = {v.x, v.y, v.z, v.w};
  union { __hip_bfloat16 h[4]; uint2 u; } H, L;
#pragma unroll
  for (int u = 0; u < 4; ++u) {
    H.h[u] = __float2bfloat16(vv[u]);
    L.h[u] = __float2bfloat16(vv[u] - __bfloat162float(H.h[u]));
  }
  unsigned short* ob = (unsigned short*)out + (r << (ks + 1)) + k;
  *(uint2*)ob = H.u;
  *(uint2*)(ob + K) = L.u;
}

// ---------------- transpose + split: WT2[nb][col][hi 512 | lo 512] = whh^T ----------------
__global__ __launch_bounds__(256) void tsplit_kernel(
    const float* __restrict__ w, __hip_bfloat16* __restrict__ wt2)
{
  __shared__ float ts[64][65];
  int bx = blockIdx.x, by = blockIdx.y, nb = blockIdx.z;
  int t = threadIdx.x;
  int tr = t >> 4, c0 = (t & 15) * 4;
  const float* wb = w + (size_t)nb * 262144;
#pragma unroll
  for (int k = 0; k < 4; ++k) {
    int r = tr + k * 16;
    float4 v = *(const float4*)(wb + (size_t)(by * 64 + r) * 512 + bx * 64 + c0);
    ts[r][c0 + 0] = v.x; ts[r][c0 + 1] = v.y;
    ts[r][c0 + 2] = v.z; ts[r][c0 + 3] = v.w;
  }
  __syncthreads();
  unsigned short* ob = (unsigned short*)wt2 + (size_t)nb * 524288;
#pragma unroll
  for (int k = 0; k < 4; ++k) {
    int r = tr + k * 16;
    float vv[4] = {ts[c0][r], ts[c0 + 1][r], ts[c0 + 2][r], ts[c0 + 3][r]};
    union { __hip_bfloat16 h[4]; uint2 u; } H, L;
#pragma unroll
    for (int j = 0; j < 4; ++j) {
      H.h[j] = __float2bfloat16(vv[j]);
      L.h[j] = __float2bfloat16(vv[j] - __bfloat162float(H.h[j]));
    }
    size_t row = (size_t)(bx * 64 + r);
    *(uint2*)(ob + row * 1024 + by * 64 + c0) = H.u;
    *(uint2*)(ob + row * 1024 + 512 + by * 64 + c0) = L.u;
  }
}

// ---------------- split-bf16 MFMA GEMM, generalized ----------------
// C = A*B^T over hi/lo segments. 128x128 tile, 256 thr, BK=32, 16x16x32 bf16.
// z-batching two-level: off = (bz/nz2)*b?1 + (bz%nz2)*b?2 (element units).
// nseg==3: Ahi*Bhi + Ahi*Blo + Alo*Bhi (lo at +loA/+loB); nseg==2: A hi-only.
// mode 0: normal epilogue (bias, Add fp32, relu, Cf fp32, C2 hi|lo at ldc2/loC2)
// mode 1: XIH scatter (conv output, hi only)
// mode 2: Cf normal + C2 as XP concat [b][f*512+n | 4096+f*512+n]
__global__ __launch_bounds__(256) void gemm_mfma(
    const __hip_bfloat16* __restrict__ A_, int ldA, long long bA1, long long bA2, int loA,
    const __hip_bfloat16* __restrict__ B_, int ldB, long long bB1, long long bB2, int loB,
    const float* __restrict__ bias, long long bBias1, long long bBias2,
    const float* __restrict__ Add, int ldadd, long long bAdd1, long long bAdd2,
    float* __restrict__ Cf, int ldcf, long long bCf1, long long bCf2,
    __hip_bfloat16* __restrict__ C2, int ldc2, int loC2, long long bC21, long long bC22,
    int nz2, int M, int N, int K, int nseg, int relu, int mode)
{
  __shared__ short sA[128 * 32];
  __shared__ short sB[128 * 32];
  int z1 = blockIdx.z / nz2, z2 = blockIdx.z % nz2;
  const short* Ab = (const short*)A_ + (long long)z1 * bA1 + (long long)z2 * bA2;
  const short* Bb = (const short*)B_ + (long long)z1 * bB1 + (long long)z2 * bB2;
  int tid = threadIdx.x, wave = tid >> 6, lane = tid & 63;
  int bm = blockIdx.y << 7, bn = blockIdx.x << 7;
  int wrow = (wave >> 1) << 6, wcol = (wave & 1) << 6;

  int sr = lane >> 2;
  int qg = (lane & 3) ^ (sr & 3);
  int ar0 = wave << 5;

  f32x4 acc[4][4];
#pragma unroll
  for (int i = 0; i < 4; ++i)
#pragma unroll
    for (int j = 0; j < 4; ++j)
      acc[i][j] = (f32x4){0.f, 0.f, 0.f, 0.f};

  int frow = lane & 15;
  int fq = lane >> 4;
  int aoffs[4], boffs[4];
#pragma unroll
  for (int i = 0; i < 4; ++i) {
    int ra = wrow + 16 * i + frow;
    aoffs[i] = ra * 32 + ((fq ^ (ra & 3)) << 3);
    int rb = wcol + 16 * i + frow;
    boffs[i] = rb * 32 + ((fq ^ (rb & 3)) << 3);
  }

  for (int seg = 0; seg < nseg; ++seg) {
    int aoff = (seg == 2) ? loA : 0;
    int boff = (seg == 1) ? loB : 0;
    const short* Aseg = Ab + aoff + (long long)(bm + ar0 + sr) * ldA + qg * 8;
    const short* Bseg = Bb + boff + (long long)(bn + ar0 + sr) * ldB + qg * 8;
    for (int ko = 0; ko < K; ko += 32) {
      gld16(Aseg + ko, &sA[ar0 * 32]);
      gld16(Aseg + ko + 16 * ldA, &sA[(ar0 + 16) * 32]);
      gld16(Bseg + ko, &sB[ar0 * 32]);
      gld16(Bseg + ko + 16 * ldB, &sB[(ar0 + 16) * 32]);
      __syncthreads();
      bf16x8 af[4], bfr[4];
#pragma unroll
      for (int i = 0; i < 4; ++i) af[i] = *(const bf16x8*)&sA[aoffs[i]];
#pragma unroll
      for (int j = 0; j < 4; ++j) bfr[j] = *(const bf16x8*)&sB[boffs[j]];
#pragma unroll
      for (int i = 0; i < 4; ++i)
#pragma unroll
        for (int j = 0; j < 4; ++j)
          acc[i][j] = __builtin_amdgcn_mfma_f32_16x16x32_bf16(
              af[i], bfr[j], acc[i][j], 0, 0, 0);
      __syncthreads();
    }
  }

  short* c2z = C2 ? (short*)C2 + (long long)z1 * bC21 + (long long)z2 * bC22 : nullptr;

  if (mode == 1) {
    // m = l (0..511), n = b*32+c -> XIH row = b*8 + l/64, col = (l%64)*32 + c
#pragma unroll
    for (int j = 0; j < 4; ++j) {
      int n = bn + wcol + 16 * j + frow;
      int bidx = n >> 5, c = n & 31;
#pragma unroll
      for (int i = 0; i < 4; ++i)
#pragma unroll
        for (int r = 0; r < 4; ++r) {
          int m = bm + wrow + 16 * i + fq * 4 + r;
          int row = bidx * 8 + (m >> 6);
          int col = (m & 63) * 32 + c;
          ((__hip_bfloat16*)c2z)[(long long)row * 2048 + col] =
              __float2bfloat16(acc[i][j][r]);
        }
    }
    return;
  }

  const float* biasz = bias ? bias + (long long)z1 * bBias1 + (long long)z2 * bBias2 : nullptr;
  const float* addz  = Add  ? Add  + (long long)z1 * bAdd1  + (long long)z2 * bAdd2  : nullptr;
  float* cfz = Cf ? Cf + (long long)z1 * bCf1 + (long long)z2 * bCf2 : nullptr;

#pragma unroll
  for (int j = 0; j < 4; ++j) {
    int n = bn + wcol + 16 * j + frow;
    float bv = biasz ? biasz[n] : 0.f;
#pragma unroll
    for (int i = 0; i < 4; ++i) {
#pragma unroll
      for (int r = 0; r < 4; ++r) {
        int m = bm + wrow + 16 * i + fq * 4 + r;
        float v = acc[i][j][r] + bv;
        if (addz) v += addz[(long long)m * ldadd + n];
        if (relu) v = fmaxf(v, 0.f);
        if (cfz) cfz[(long long)m * ldcf + n] = v;
        if (c2z) {
          __hip_bfloat16 h = __float2bfloat16(v);
          __hip_bfloat16 l = __float2bfloat16(v - __bfloat162float(h));
          if (mode == 2) {
            long long off = (long long)(m >> 3) * 8192 + (m & 7) * 512 + n;
            ((__hip_bfloat16*)c2z)[off] = h;
            ((__hip_bfloat16*)c2z)[off + 4096] = l;
          } else {
            ((__hip_bfloat16*)c2z)[(long long)m * ldc2 + n] = h;
            ((__hip_bfloat16*)c2z)[(long long)m * ldc2 + loC2 + n] = l;
          }
        }
      }
    }
  }
}

// ---------------- LayerNorm over 512, writes bf16 hi/lo [row, 1024] ----------------
__global__ __launch_bounds__(256) void ln_kernel(
    const float* __restrict__ p, const float* __restrict__ g,
    const float* __restrict__ bb, __hip_bfloat16* __restrict__ p2)
{
  int row = blockIdx.x;              // NB*B*4 = 4096
  int nb = row >> 10;
  const float* pr = p + (size_t)row * 512;
  int tid = threadIdx.x;
  float v0 = pr[tid], v1 = pr[tid + 256];
  float s = v0 + v1, s2 = v0 * v0 + v1 * v1;
#pragma unroll
  for (int o = 32; o > 0; o >>= 1) {
    s += __shfl_down(s, o);
    s2 += __shfl_down(s2, o);
  }
  __shared__ float rs[4];
  __shared__ float rs2[4];
  int w = tid >> 6;
  if ((tid & 63) == 0) { rs[w] = s; rs2[w] = s2; }
  __syncthreads();
  s = rs[0] + rs[1] + rs[2] + rs[3];
  s2 = rs2[0] + rs2[1] + rs2[2] + rs2[3];
  float mval = s * (1.f / 512.f);
  float var = s2 * (1.f / 512.f) - mval * mval;
  float r = 1.f / sqrtf(var + EPSF);
  const float* gn = g + nb * 512;
  const float* bn = bb + nb * 512;
  float y0 = (v0 - mval) * r * gn[tid] + bn[tid];
  float y1 = (v1 - mval) * r * gn[tid + 256] + bn[tid + 256];
  __hip_bfloat16* o2 = p2 + (size_t)nb * 1048576 + (size_t)(row & 1023) * 1024;
  __hip_bfloat16 h0 = __float2bfloat16(y0);
  __hip_bfloat16 h1 = __float2bfloat16(y1);
  o2[tid] = h0;
  o2[tid + 256] = h1;
  o2[512 + tid] = __float2bfloat16(y0 - __bfloat162float(h0));
  o2[768 + tid] = __float2bfloat16(y1 - __bfloat162float(h1));
}

// ---------------- final: out = (sum_nb deco) * std + mean ----------------
__global__ __launch_bounds__(256) void final_kernel(
    const float* __restrict__ deco, const float* __restrict__ meanp,
    const float* __restrict__ stdp, float* __restrict__ out)
{
  int t = blockIdx.x * 256 + threadIdx.x;
  int b = t >> 11;
  int r = t & 2047;
  int p = (r >> 3) & 63;
  int cq = r & 7;
  size_t base = ((size_t)(b * 4 + (r >> 9))) * 2048 + p * 32 + cq * 4;
  const size_t nbs = 1024ull * 2048ull;
  float4 a0 = *(const float4*)(deco + base);
  float4 a1 = *(const float4*)(deco + nbs + base);
  float4 a2 = *(const float4*)(deco + 2 * nbs + base);
  float4 a3 = *(const float4*)(deco + 3 * nbs + base);
  float4 m4 = *(const float4*)(meanp + b * 32 + cq * 4);
  float4 s4 = *(const float4*)(stdp + b * 32 + cq * 4);
  float4 o;
  o.x = (a0.x + a1.x + a2.x + a3.x) * s4.x + m4.x;
  o.y = (a0.y + a1.y + a2.y + a3.y) * s4.y + m4.y;
  o.z = (a0.z + a1.z + a2.z + a3.z) * s4.z + m4.z;
  o.w = (a0.w + a1.w + a2.w + a3.w) * s4.w + m4.w;
  *(float4*)(out + (size_t)t * 4) = o;
}

extern "C" void kernel_launch(void* const* d_in, const int* in_sizes, int n_in,
                              void* d_out, int out_size, void* d_ws, size_t ws_size,
                              hipStream_t stream) {
  const float* x_enc  = (const float*)d_in[0];
  const float* mask_w = (const float*)d_in[4];
  const float* enc_w1 = (const float*)d_in[5];
  const float* enc_b1 = (const float*)d_in[6];
  const float* enc_w2 = (const float*)d_in[7];
  const float* enc_b2 = (const float*)d_in[8];
  const float* wxh    = (const float*)d_in[9];
  const float* whh    = (const float*)d_in[10];
  const float* ln_g   = (const float*)d_in[11];
  const float* ln_b   = (const float*)d_in[12];
  const float* dec_w1 = (const float*)d_in[13];
  const float* dec_b1 = (const float*)d_in[14];
  const float* dec_w2 = (const float*)d_in[15];
  const float* dec_b2 = (const float*)d_in[16];
  float* out = (float*)d_out;

  typedef __hip_bfloat16 bf;
  char* W = (char*)d_ws;
  float* MEAN = (float*)(W);
  float* STD  = (float*)(W + 32768);
  float* RSTD = (float*)(W + 65536);
  float* KF   = (float*)(W + 98304);
  char* B0 = W + 131072;
  // ---- lifetime-checked layout (MB offsets from B0); peak 112 MB ----
  // phase 1
  bf* XIH   = (bf*)(B0);                    // [0,32)
  bf* XNB   = (bf*)(B0 + 33554432);         // [32,48)   dead after conv
  bf* CM    = (bf*)(B0 + 50331648);         // [48,52)   dead after conv
  bf* WW    = (bf*)(B0 + 33554432);         // [32,64)   written after conv, dead after enc1
  bf* ENCB2 = (bf*)(B0 + 67108864);         // [64,96)   dead after enc2
  // phase 2 weight splits (after enc1; [0,32) free)
  bf* EW2   = (bf*)(B0);                    // [0,8)
  bf* WXH2  = (bf*)(B0 + 8388608);          // [8,12)
  bf* DW1   = (bf*)(B0 + 12582912);         // [12,20)   read at dec1
  bf* WSP   = (bf*)(B0 + 20971520);         // [20,24)
  bf* W2SP  = (bf*)(B0 + 25165824);         // [24,28)
  bf* WTSP  = (bf*)(B0 + 29360128);         // [28,32)
  bf* ENC22 = (bf*)(B0 + 33554432);         // [32,48)   dead after xp
  float* XP = (float*)(B0 + 50331648);      // [48,64)   dead after y-combine
  bf* XP2   = (bf*)(B0 + 67108864);         // [64,80)   dead after y-combine
  float* YF = (float*)(B0 + 83886080);      // [80,88)   dead after Horner-3
  bf* Y2    = (bf*)(B0 + 92274688);         // [88,96)   dead after Horner-1
  bf* H2    = (bf*)(B0 + 100663296);        // [96,98)
  bf* H22   = (bf*)(B0 + 102760448);        // [98,100)
  bf* P12   = (bf*)(B0 + 104857600);        // [100,104)
  float* PREDS = (float*)(B0 + 109051904);  // [104,112)
  bf* PREDS2   = (bf*)(B0 + 33554432);      // [32,40)   written at ln (ENC22 dead)
  bf* DW2   = (bf*)(B0 + 50331648);         // [48,80)   split after y-combine
  bf* DBUF2 = (bf*)(B0 + 83886080);         // [80,96)   dec1 out (YF/Y2 dead)
  float* DECO = (float*)(B0);               // [0,32)    dec2 out (weights dead)

  stats_kernel<<<256, 256, 0, stream>>>(x_enc, MEAN, STD, RSTD);
  kfilt_kernel<<<8, 256, 0, stream>>>(mask_w, KF);
  xprep_kernel<<<256, 256, 0, stream>>>(x_enc, MEAN, RSTD, XNB);
  cmat_kernel<<<512, 256, 0, stream>>>(KF, CM);

  // conv as MFMA GEMM (A=CM hi-only, nseg=2): per nb [512,512] @ [8192,512]^T -> XIH scatter
  gemm_mfma<<<dim3(64, 4, 4), 256, 0, stream>>>(
      CM, 1024, 524288LL, 0LL, 0, XNB, 1024, 0LL, 0LL, 512,
      nullptr, 0, 0, nullptr, 0, 0, 0, nullptr, 0, 0, 0,
      XIH, 0, 0, 4194304LL, 0LL, 1, 512, 8192, 512, 2, 0, 1);

  // enc1: M=2048 N=1024 K=2048, A hi-only (nseg=2), relu, split-out
  split_kernel<<<8192, 256, 0, stream>>>(enc_w1, WW, 11);
  gemm_mfma<<<dim3(8, 16, 4), 256, 0, stream>>>(
      XIH, 2048, 4194304LL, 0LL, 0, WW, 4096, 4194304LL, 0LL, 2048,
      enc_b1, 1024LL, 0LL, nullptr, 0, 0, 0, nullptr, 0, 0, 0,
      ENCB2, 2048, 1024, 4194304LL, 0LL, 1, 2048, 1024, 2048, 2, 1, 0);

  split_kernel<<<2048, 256, 0, stream>>>(enc_w2, EW2, 10);
  split_kernel<<<1024, 256, 0, stream>>>(wxh, WXH2, 9);
  split_kernel<<<2048, 256, 0, stream>>>(dec_w1, DW1, 9);
  split_kernel<<<1024, 256, 0, stream>>>(whh, WSP, 9);
  tsplit_kernel<<<dim3(8, 8, 4), 256, 0, stream>>>(whh, WTSP);

  // enc2: M=2048 N=512 K=1024, nseg=3, split-out
  gemm_mfma<<<dim3(4, 16, 4), 256, 0, stream>>>(
      ENCB2, 2048, 4194304LL, 0LL, 1024, EW2, 2048, 1048576LL, 0LL, 1024,
      enc_b2, 512LL, 0LL, nullptr, 0, 0, 0, nullptr, 0, 0, 0,
      ENC22, 1024, 512, 2097152LL, 0LL, 1, 2048, 512, 1024, 3, 0, 0);

  // xp = enc2 @ wxh^T: fp32 out + XP2 hi|lo-concat (mode 2)
  gemm_mfma<<<dim3(4, 16, 4), 256, 0, stream>>>(
      ENC22, 1024, 2097152LL, 0LL, 512, WXH2, 1024, 524288LL, 0LL, 512,
      nullptr, 0, 0, nullptr, 0, 0, 0, XP, 512, 1048576LL, 0LL,
      XP2, 0, 0, 2097152LL, 0LL, 1, 2048, 512, 512, 3, 0, 2);

  // W2 = W @ W  (A=WSP, B=WTSP) -> split-out W2SP
  gemm_mfma<<<dim3(4, 4, 4), 256, 0, stream>>>(
      WSP, 1024, 524288LL, 0LL, 512, WTSP, 1024, 524288LL, 0LL, 512,
      nullptr, 0, 0, nullptr, 0, 0, 0, nullptr, 0, 0, 0,
      W2SP, 1024, 512, 524288LL, 0LL, 1, 512, 512, 512, 3, 0, 0);

  // y_j = xp_{2j} @ W^T + xp_{2j+1}   (z1 = j, z2 = nb, 16 total)
  gemm_mfma<<<dim3(4, 2, 16), 256, 0, stream>>>(
      XP2, 8192, 1024LL, 2097152LL, 4096, WSP, 1024, 0LL, 524288LL, 512,
      nullptr, 0, 0, XP + 512, 4096, 1024LL, 1048576LL,
      YF, 512, 524288LL, 131072LL,
      Y2, 1024, 512, 1048576LL, 262144LL, 4, 256, 512, 512, 3, 0, 0);

  // split dec_w2 now (XP/XP2 regions dead)
  split_kernel<<<8192, 256, 0, stream>>>(dec_w2, DW2, 10);

  // Horner with W2: h1 = y0@W2^T + y1; h2 = h1@W2^T + y2; h = h2@W2^T + y3
  gemm_mfma<<<dim3(4, 2, 4), 256, 0, stream>>>(
      Y2, 1024, 0LL, 262144LL, 512, W2SP, 1024, 0LL, 524288LL, 512,
      nullptr, 0, 0, YF + 524288, 512, 0LL, 131072LL, nullptr, 0, 0, 0,
      H2, 1024, 512, 0LL, 262144LL, 4, 256, 512, 512, 3, 0, 0);
  gemm_mfma<<<dim3(4, 2, 4), 256, 0, stream>>>(
      H2, 1024, 0LL, 262144LL, 512, W2SP, 1024, 0LL, 524288LL, 512,
      nullptr, 0, 0, YF + 1048576, 512, 0LL, 131072LL, nullptr, 0, 0, 0,
      H22, 1024, 512, 0LL, 262144LL, 4, 256, 512, 512, 3, 0, 0);
  gemm_mfma<<<dim3(4, 2, 4), 256, 0, stream>>>(
      H22, 1024, 0LL, 262144LL, 512, W2SP, 1024, 0LL, 524288LL, 512,
      nullptr, 0, 0, YF + 1572864, 512, 0LL, 131072LL, nullptr, 0, 0, 0,
      H2, 1024, 512, 0LL, 262144LL, 4, 256, 512, 512, 3, 0, 0);

  // free-run A: p1 = h@W^T (z1=0), p2 = h@W2^T (z1=1)
  gemm_mfma<<<dim3(4, 2, 8), 256, 0, stream>>>(
      H2, 1024, 0LL, 262144LL, 512, WSP, 1024, 2097152LL, 524288LL, 512,
      nullptr, 0, 0, nullptr, 0, 0, 0, PREDS, 2048, 512LL, 524288LL,
      P12, 1024, 512, 1048576LL, 262144LL, 4, 256, 512, 512, 3, 0, 0);
  // free-run B: p3 = p1@W2^T, p4 = p2@W2^T
  gemm_mfma<<<dim3(4, 2, 8), 256, 0, stream>>>(
      P12, 1024, 1048576LL, 262144LL, 512, W2SP, 1024, 0LL, 524288LL, 512,
      nullptr, 0, 0, nullptr, 0, 0, 0, PREDS + 1024, 2048, 512LL, 524288LL,
      nullptr, 0, 0, 0LL, 0LL, 4, 256, 512, 512, 3, 0, 0);

  ln_kernel<<<4096, 256, 0, stream>>>(PREDS, ln_g, ln_b, PREDS2);

  // dec1: M=1024 N=1024 K=512, nseg=3, relu, split-out
  gemm_mfma<<<dim3(8, 8, 4), 256, 0, stream>>>(
      PREDS2, 1024, 1048576LL, 0LL, 512, DW1, 1024, 1048576LL, 0LL, 512,
      dec_b1, 1024LL, 0LL, nullptr, 0, 0, 0, nullptr, 0, 0, 0,
      DBUF2, 2048, 1024, 2097152LL, 0LL, 1, 1024, 1024, 512, 3, 1, 0);
  // dec2: M=1024 N=2048 K=1024, nseg=3, fp32 out
  gemm_mfma<<<dim3(16, 8, 4), 256, 0, stream>>>(
      DBUF2, 2048, 2097152LL, 0LL, 1024, DW2, 2048, 4194304LL, 0LL, 1024,
      dec_b2, 2048LL, 0LL, nullptr, 0, 0, 0, DECO, 2048, 2097152LL, 0LL,
      nullptr, 0, 0, 0LL, 0LL, 1, 1024, 2048, 1024, 3, 0, 0);

  final_kernel<<<2048, 256, 0, stream>>>(DECO, MEAN, STD, out);
}

// Round 6
// 911.625 us; speedup vs baseline: 1.1959x; 1.0635x over previous
//
#include <hip/hip_runtime.h>
#include <hip/hip_bf16.h>
#include <math.h>

#define EPSF 1e-5f

typedef __attribute__((ext_vector_type(8))) short bf16x8;
typedef __attribute__((ext_vector_type(4))) float f32x4;

__device__ __forceinline__ void gld16(const void* g, void* l) {
  __builtin_amdgcn_global_load_lds(
      (const __attribute__((address_space(1))) unsigned int*)g,
      (__attribute__((address_space(3))) unsigned int*)l, 16, 0, 0);
}

// ---------------- instance-norm stats over time axis ----------------
__global__ __launch_bounds__(256) void stats_kernel(
    const float* __restrict__ x, float* __restrict__ meanp,
    float* __restrict__ stdp, float* __restrict__ rstdp)
{
  int b = blockIdx.x;
  int tid = threadIdx.x;
  int c = tid & 31, ls = tid >> 5;
  const float* xb = x + (size_t)b * 16384;
  float s = 0.f, s2 = 0.f;
  for (int l = ls; l < 512; l += 8) {
    float v = xb[l * 32 + c];
    s += v; s2 += v * v;
  }
  __shared__ float sb[8][32];
  __shared__ float sb2[8][32];
  sb[ls][c] = s; sb2[ls][c] = s2;
  __syncthreads();
  if (ls == 0) {
#pragma unroll
    for (int i = 1; i < 8; ++i) { s += sb[i][c]; s2 += sb2[i][c]; }
    float m = s * (1.f / 512.f);
    float var = s2 * (1.f / 512.f) - m * m;
    float sd = sqrtf(var + EPSF);
    meanp[b * 32 + c] = m;
    stdp[b * 32 + c] = sd;
    rstdp[b * 32 + c] = 1.f / sd;
  }
}

// ---------------- Fourier-mask -> time-domain filter taps (duplicated) ----------------
__global__ __launch_bounds__(256) void kfilt_kernel(
    const float* __restrict__ mw, float* __restrict__ kf)
{
  int gid = blockIdx.x * 256 + threadIdx.x;
  int nb = gid >> 9, t = gid & 511;
  const float* m = mw + nb * 257;
  float s0 = 1.f / (1.f + expf(-m[0]));
  float sN = 1.f / (1.f + expf(-m[256]));
  float acc = s0 + ((t & 1) ? -sN : sN);
  for (int f = 1; f < 256; ++f) {
    float sig = 1.f / (1.f + expf(-m[f]));
    int tf = (t * f) & 511;
    acc += 2.f * sig * cosf(6.28318530717958647f * (float)tf * (1.f / 512.f));
  }
  float kv = acc * (1.f / 512.f);
  kf[nb * 1024 + t] = kv;
  kf[nb * 1024 + t + 512] = kv;
}

// ---------------- x -> normalized, transposed, hi/lo split: XNB[b*32+c][l' | l'+512] ----------------
__global__ __launch_bounds__(256) void xprep_kernel(
    const float* __restrict__ x, const float* __restrict__ meanp,
    const float* __restrict__ rstdp, __hip_bfloat16* __restrict__ xnb)
{
  __shared__ float xs[512 * 33];
  int b = blockIdx.x, tid = threadIdx.x;
  const float* xb = x + (size_t)b * 16384;
#pragma unroll
  for (int i = 0; i < 16; ++i) {
    int idx4 = tid + i * 256;
    int l = idx4 >> 3, c0 = (idx4 & 7) * 4;
    float4 v = *(const float4*)(xb + idx4 * 4);
    xs[l * 33 + c0 + 0] = v.x;
    xs[l * 33 + c0 + 1] = v.y;
    xs[l * 33 + c0 + 2] = v.z;
    xs[l * 33 + c0 + 3] = v.w;
  }
  __syncthreads();
  for (int c = 0; c < 32; ++c) {
    float m = meanp[b * 32 + c];
    float r = rstdp[b * 32 + c];
    int l = tid * 2;
    float v0 = (xs[l * 33 + c] - m) * r;
    float v1 = (xs[(l + 1) * 33 + c] - m) * r;
    __hip_bfloat16 h0 = __float2bfloat16(v0);
    __hip_bfloat16 h1 = __float2bfloat16(v1);
    union { __hip_bfloat16 h[2]; unsigned int u; } H, L;
    H.h[0] = h0; H.h[1] = h1;
    L.h[0] = __float2bfloat16(v0 - __bfloat162float(h0));
    L.h[1] = __float2bfloat16(v1 - __bfloat162float(h1));
    unsigned int* dst =
        (unsigned int*)((unsigned short*)xnb + ((size_t)(b * 32 + c)) * 1024 + l);
    dst[0] = H.u;
    dst[256] = L.u;
  }
}

// ---------------- circulant matrix build: CM[nb][l][l' | l'+512] bf16 hi|lo ----------------
__global__ __launch_bounds__(256) void cmat_kernel(
    const float* __restrict__ kf, __hip_bfloat16* __restrict__ cm)
{
  int t = threadIdx.x;
  int row = blockIdx.x * 4 + (t >> 6);
  int nb = row >> 9, l = row & 511;
  int lp0 = (t & 63) * 8;
  union { __hip_bfloat16 h[8]; uint4 u; } H, L;
#pragma unroll
  for (int j = 0; j < 8; ++j) {
    float v = kf[nb * 1024 + 512 + l - (lp0 + j)];
    __hip_bfloat16 h = __float2bfloat16(v);
    H.h[j] = h;
    L.h[j] = __float2bfloat16(v - __bfloat162float(h));
  }
  unsigned short* dst = (unsigned short*)cm + (size_t)row * 1024 + lp0;
  *(uint4*)dst = H.u;
  *(uint4*)(dst + 512) = L.u;
}

// ---------------- fp32 -> bf16 hi/lo split: in [rows,K] -> out [rows,2K] ----------------
__global__ __launch_bounds__(256) void split_kernel(
    const float* __restrict__ in, __hip_bfloat16* __restrict__ out, int ks)
{
  int t = blockIdx.x * 256 + threadIdx.x;
  long long idx = (long long)t * 4;
  int K = 1 << ks;
  long long r = idx >> ks;
  int k = (int)(idx & (K - 1));
  float4 v = *(const float4*)(in + idx);
  float vv[4] = {v.x, v.y, v.z, v.w};
  union { __hip_bfloat16 h[4]; uint2 u; } H, L;
#pragma unroll
  for (int u = 0; u < 4; ++u) {
    H.h[u] = __float2bfloat16(vv[u]);
    L.h[u] = __float2bfloat16(vv[u] - __bfloat162float(H.h[u]));
  }
  unsigned short* ob = (unsigned short*)out + (r << (ks + 1)) + k;
  *(uint2*)ob = H.u;
  *(uint2*)(ob + K) = L.u;
}

// ---------------- transpose + split: WT2[nb][col][hi 512 | lo 512] = whh^T ----------------
__global__ __launch_bounds__(256) void tsplit_kernel(
    const float* __restrict__ w, __hip_bfloat16* __restrict__ wt2)
{
  __shared__ float ts[64][65];
  int bx = blockIdx.x, by = blockIdx.y, nb = blockIdx.z;
  int t = threadIdx.x;
  int tr = t >> 4, c0 = (t & 15) * 4;
  const float* wb = w + (size_t)nb * 262144;
#pragma unroll
  for (int k = 0; k < 4; ++k) {
    int r = tr + k * 16;
    float4 v = *(const float4*)(wb + (size_t)(by * 64 + r) * 512 + bx * 64 + c0);
    ts[r][c0 + 0] = v.x; ts[r][c0 + 1] = v.y;
    ts[r][c0 + 2] = v.z; ts[r][c0 + 3] = v.w;
  }
  __syncthreads();
  unsigned short* ob = (unsigned short*)wt2 + (size_t)nb * 524288;
#pragma unroll
  for (int k = 0; k < 4; ++k) {
    int r = tr + k * 16;
    float vv[4] = {ts[c0][r], ts[c0 + 1][r], ts[c0 + 2][r], ts[c0 + 3][r]};
    union { __hip_bfloat16 h[4]; uint2 u; } H, L;
#pragma unroll
    for (int j = 0; j < 4; ++j) {
      H.h[j] = __float2bfloat16(vv[j]);
      L.h[j] = __float2bfloat16(vv[j] - __bfloat162float(H.h[j]));
    }
    size_t row = (size_t)(bx * 64 + r);
    *(uint2*)(ob + row * 1024 + by * 64 + c0) = H.u;
    *(uint2*)(ob + row * 1024 + 512 + by * 64 + c0) = L.u;
  }
}

// ---------------- split-bf16 MFMA GEMM, fused-segment K-loop ----------------
// C = A*B^T. 128x128 tile, 256 thr, BK=32, 16x16x32 bf16 MFMA.
// Single K-pass staging Ahi[,Alo],Bhi,Blo per chunk; per frag pair:
//   nseg3: acc += Ahi*Bhi + Ahi*Blo + Alo*Bhi     nseg2: acc += Ahi*Bhi + Ahi*Blo
// z-batching two-level: off = (bz/nz2)*b?1 + (bz%nz2)*b?2 (element units).
// mode 0: normal epilogue (bias, Add fp32, relu, Cf fp32, C2 hi|lo at ldc2/loC2)
// mode 1: XIH scatter (conv output, hi only)
// mode 2: Cf normal + C2 as XP concat [b][f*512+n | 4096+f*512+n]
__global__ __launch_bounds__(256) void gemm_mfma(
    const __hip_bfloat16* __restrict__ A_, int ldA, long long bA1, long long bA2, int loA,
    const __hip_bfloat16* __restrict__ B_, int ldB, long long bB1, long long bB2, int loB,
    const float* __restrict__ bias, long long bBias1, long long bBias2,
    const float* __restrict__ Add, int ldadd, long long bAdd1, long long bAdd2,
    float* __restrict__ Cf, int ldcf, long long bCf1, long long bCf2,
    __hip_bfloat16* __restrict__ C2, int ldc2, int loC2, long long bC21, long long bC22,
    int nz2, int M, int N, int K, int nseg, int relu, int mode)
{
  __shared__ short sAh[128 * 32];
  __shared__ short sAl[128 * 32];
  __shared__ short sBh[128 * 32];
  __shared__ short sBl[128 * 32];
  int z1 = blockIdx.z / nz2, z2 = blockIdx.z % nz2;
  const short* Ab = (const short*)A_ + (long long)z1 * bA1 + (long long)z2 * bA2;
  const short* Bb = (const short*)B_ + (long long)z1 * bB1 + (long long)z2 * bB2;
  int tid = threadIdx.x, wave = tid >> 6, lane = tid & 63;
  int bm = blockIdx.y << 7, bn = blockIdx.x << 7;
  int wrow = (wave >> 1) << 6, wcol = (wave & 1) << 6;

  int sr = lane >> 2;
  int qg = (lane & 3) ^ (sr & 3);
  int ar0 = wave << 5;

  f32x4 acc[4][4];
#pragma unroll
  for (int i = 0; i < 4; ++i)
#pragma unroll
    for (int j = 0; j < 4; ++j)
      acc[i][j] = (f32x4){0.f, 0.f, 0.f, 0.f};

  int frow = lane & 15;
  int fq = lane >> 4;
  int aoffs[4], boffs[4];
#pragma unroll
  for (int i = 0; i < 4; ++i) {
    int ra = wrow + 16 * i + frow;
    aoffs[i] = ra * 32 + ((fq ^ (ra & 3)) << 3);
    int rb = wcol + 16 * i + frow;
    boffs[i] = rb * 32 + ((fq ^ (rb & 3)) << 3);
  }

  const short* Ah = Ab + (long long)(bm + ar0 + sr) * ldA + qg * 8;
  const short* Al = Ah + loA;
  const short* Bh = Bb + (long long)(bn + ar0 + sr) * ldB + qg * 8;
  const short* Bl = Bh + loB;
  int three = (nseg == 3);

  for (int ko = 0; ko < K; ko += 32) {
    gld16(Ah + ko, &sAh[ar0 * 32]);
    gld16(Ah + ko + 16 * ldA, &sAh[(ar0 + 16) * 32]);
    if (three) {
      gld16(Al + ko, &sAl[ar0 * 32]);
      gld16(Al + ko + 16 * ldA, &sAl[(ar0 + 16) * 32]);
    }
    gld16(Bh + ko, &sBh[ar0 * 32]);
    gld16(Bh + ko + 16 * ldB, &sBh[(ar0 + 16) * 32]);
    gld16(Bl + ko, &sBl[ar0 * 32]);
    gld16(Bl + ko + 16 * ldB, &sBl[(ar0 + 16) * 32]);
    __syncthreads();
    bf16x8 ah[4], al[4], bh[4], bl[4];
#pragma unroll
    for (int i = 0; i < 4; ++i) ah[i] = *(const bf16x8*)&sAh[aoffs[i]];
#pragma unroll
    for (int j = 0; j < 4; ++j) bh[j] = *(const bf16x8*)&sBh[boffs[j]];
#pragma unroll
    for (int j = 0; j < 4; ++j) bl[j] = *(const bf16x8*)&sBl[boffs[j]];
    if (three) {
#pragma unroll
      for (int i = 0; i < 4; ++i) al[i] = *(const bf16x8*)&sAl[aoffs[i]];
    }
#pragma unroll
    for (int i = 0; i < 4; ++i)
#pragma unroll
      for (int j = 0; j < 4; ++j) {
        acc[i][j] = __builtin_amdgcn_mfma_f32_16x16x32_bf16(ah[i], bh[j], acc[i][j], 0, 0, 0);
        acc[i][j] = __builtin_amdgcn_mfma_f32_16x16x32_bf16(ah[i], bl[j], acc[i][j], 0, 0, 0);
        if (three)
          acc[i][j] = __builtin_amdgcn_mfma_f32_16x16x32_bf16(al[i], bh[j], acc[i][j], 0, 0, 0);
      }
    __syncthreads();
  }

  short* c2z = C2 ? (short*)C2 + (long long)z1 * bC21 + (long long)z2 * bC22 : nullptr;

  if (mode == 1) {
    // m = l (0..511), n = b*32+c -> XIH row = b*8 + l/64, col = (l%64)*32 + c
#pragma unroll
    for (int j = 0; j < 4; ++j) {
      int n = bn + wcol + 16 * j + frow;
      int bidx = n >> 5, c = n & 31;
#pragma unroll
      for (int i = 0; i < 4; ++i)
#pragma unroll
        for (int r = 0; r < 4; ++r) {
          int m = bm + wrow + 16 * i + fq * 4 + r;
          int row = bidx * 8 + (m >> 6);
          int col = (m & 63) * 32 + c;
          ((__hip_bfloat16*)c2z)[(long long)row * 2048 + col] =
              __float2bfloat16(acc[i][j][r]);
        }
    }
    return;
  }

  const float* biasz = bias ? bias + (long long)z1 * bBias1 + (long long)z2 * bBias2 : nullptr;
  const float* addz  = Add  ? Add  + (long long)z1 * bAdd1  + (long long)z2 * bAdd2  : nullptr;
  float* cfz = Cf ? Cf + (long long)z1 * bCf1 + (long long)z2 * bCf2 : nullptr;

#pragma unroll
  for (int j = 0; j < 4; ++j) {
    int n = bn + wcol + 16 * j + frow;
    float bv = biasz ? biasz[n] : 0.f;
#pragma unroll
    for (int i = 0; i < 4; ++i) {
#pragma unroll
      for (int r = 0; r < 4; ++r) {
        int m = bm + wrow + 16 * i + fq * 4 + r;
        float v = acc[i][j][r] + bv;
        if (addz) v += addz[(long long)m * ldadd + n];
        if (relu) v = fmaxf(v, 0.f);
        if (cfz) cfz[(long long)m * ldcf + n] = v;
        if (c2z) {
          __hip_bfloat16 h = __float2bfloat16(v);
          __hip_bfloat16 l = __float2bfloat16(v - __bfloat162float(h));
          if (mode == 2) {
            long long off = (long long)(m >> 3) * 8192 + (m & 7) * 512 + n;
            ((__hip_bfloat16*)c2z)[off] = h;
            ((__hip_bfloat16*)c2z)[off + 4096] = l;
          } else {
            ((__hip_bfloat16*)c2z)[(long long)m * ldc2 + n] = h;
            ((__hip_bfloat16*)c2z)[(long long)m * ldc2 + loC2 + n] = l;
          }
        }
      }
    }
  }
}

// ---------------- LayerNorm over 512, writes bf16 hi/lo [row, 1024] ----------------
__global__ __launch_bounds__(256) void ln_kernel(
    const float* __restrict__ p, const float* __restrict__ g,
    const float* __restrict__ bb, __hip_bfloat16* __restrict__ p2)
{
  int row = blockIdx.x;              // NB*B*4 = 4096
  int nb = row >> 10;
  const float* pr = p + (size_t)row * 512;
  int tid = threadIdx.x;
  float v0 = pr[tid], v1 = pr[tid + 256];
  float s = v0 + v1, s2 = v0 * v0 + v1 * v1;
#pragma unroll
  for (int o = 32; o > 0; o >>= 1) {
    s += __shfl_down(s, o);
    s2 += __shfl_down(s2, o);
  }
  __shared__ float rs[4];
  __shared__ float rs2[4];
  int w = tid >> 6;
  if ((tid & 63) == 0) { rs[w] = s; rs2[w] = s2; }
  __syncthreads();
  s = rs[0] + rs[1] + rs[2] + rs[3];
  s2 = rs2[0] + rs2[1] + rs2[2] + rs2[3];
  float mval = s * (1.f / 512.f);
  float var = s2 * (1.f / 512.f) - mval * mval;
  float r = 1.f / sqrtf(var + EPSF);
  const float* gn = g + nb * 512;
  const float* bn = bb + nb * 512;
  float y0 = (v0 - mval) * r * gn[tid] + bn[tid];
  float y1 = (v1 - mval) * r * gn[tid + 256] + bn[tid + 256];
  __hip_bfloat16* o2 = p2 + (size_t)nb * 1048576 + (size_t)(row & 1023) * 1024;
  __hip_bfloat16 h0 = __float2bfloat16(y0);
  __hip_bfloat16 h1 = __float2bfloat16(y1);
  o2[tid] = h0;
  o2[tid + 256] = h1;
  o2[512 + tid] = __float2bfloat16(y0 - __bfloat162float(h0));
  o2[768 + tid] = __float2bfloat16(y1 - __bfloat162float(h1));
}

// ---------------- final: out = (sum_nb deco) * std + mean ----------------
__global__ __launch_bounds__(256) void final_kernel(
    const float* __restrict__ deco, const float* __restrict__ meanp,
    const float* __restrict__ stdp, float* __restrict__ out)
{
  int t = blockIdx.x * 256 + threadIdx.x;
  int b = t >> 11;
  int r = t & 2047;
  int p = (r >> 3) & 63;
  int cq = r & 7;
  size_t base = ((size_t)(b * 4 + (r >> 9))) * 2048 + p * 32 + cq * 4;
  const size_t nbs = 1024ull * 2048ull;
  float4 a0 = *(const float4*)(deco + base);
  float4 a1 = *(const float4*)(deco + nbs + base);
  float4 a2 = *(const float4*)(deco + 2 * nbs + base);
  float4 a3 = *(const float4*)(deco + 3 * nbs + base);
  float4 m4 = *(const float4*)(meanp + b * 32 + cq * 4);
  float4 s4 = *(const float4*)(stdp + b * 32 + cq * 4);
  float4 o;
  o.x = (a0.x + a1.x + a2.x + a3.x) * s4.x + m4.x;
  o.y = (a0.y + a1.y + a2.y + a3.y) * s4.y + m4.y;
  o.z = (a0.z + a1.z + a2.z + a3.z) * s4.z + m4.z;
  o.w = (a0.w + a1.w + a2.w + a3.w) * s4.w + m4.w;
  *(float4*)(out + (size_t)t * 4) = o;
}

extern "C" void kernel_launch(void* const* d_in, const int* in_sizes, int n_in,
                              void* d_out, int out_size, void* d_ws, size_t ws_size,
                              hipStream_t stream) {
  const float* x_enc  = (const float*)d_in[0];
  const float* mask_w = (const float*)d_in[4];
  const float* enc_w1 = (const float*)d_in[5];
  const float* enc_b1 = (const float*)d_in[6];
  const float* enc_w2 = (const float*)d_in[7];
  const float* enc_b2 = (const float*)d_in[8];
  const float* wxh    = (const float*)d_in[9];
  const float* whh    = (const float*)d_in[10];
  const float* ln_g   = (const float*)d_in[11];
  const float* ln_b   = (const float*)d_in[12];
  const float* dec_w1 = (const float*)d_in[13];
  const float* dec_b1 = (const float*)d_in[14];
  const float* dec_w2 = (const float*)d_in[15];
  const float* dec_b2 = (const float*)d_in[16];
  float* out = (float*)d_out;

  typedef __hip_bfloat16 bf;
  char* W = (char*)d_ws;
  float* MEAN = (float*)(W);
  float* STD  = (float*)(W + 32768);
  float* RSTD = (float*)(W + 65536);
  float* KF   = (float*)(W + 98304);
  char* B0 = W + 131072;
  // ---- lifetime-checked layout (MB offsets from B0); peak 112 MB ----
  bf* XIH   = (bf*)(B0);                    // [0,32)
  bf* XNB   = (bf*)(B0 + 33554432);         // [32,48)   dead after conv
  bf* CM    = (bf*)(B0 + 50331648);         // [48,52)   dead after conv
  bf* WW    = (bf*)(B0 + 33554432);         // [32,64)   written after conv, dead after enc1
  bf* ENCB2 = (bf*)(B0 + 67108864);         // [64,96)   dead after enc2
  bf* EW2   = (bf*)(B0);                    // [0,8)
  bf* WXH2  = (bf*)(B0 + 8388608);          // [8,12)
  bf* DW1   = (bf*)(B0 + 12582912);         // [12,20)   read at dec1
  bf* WSP   = (bf*)(B0 + 20971520);         // [20,24)
  bf* W2SP  = (bf*)(B0 + 25165824);         // [24,28)
  bf* WTSP  = (bf*)(B0 + 29360128);         // [28,32)
  bf* ENC22 = (bf*)(B0 + 33554432);         // [32,48)   dead after xp
  float* XP = (float*)(B0 + 50331648);      // [48,64)   dead after y-combine
  bf* XP2   = (bf*)(B0 + 67108864);         // [64,80)   dead after y-combine
  float* YF = (float*)(B0 + 83886080);      // [80,88)   dead after Horner-3
  bf* Y2    = (bf*)(B0 + 92274688);         // [88,96)   dead after Horner-1
  bf* H2    = (bf*)(B0 + 100663296);        // [96,98)
  bf* H22   = (bf*)(B0 + 102760448);        // [98,100)
  bf* P12   = (bf*)(B0 + 104857600);        // [100,104)
  float* PREDS = (float*)(B0 + 109051904);  // [104,112)
  bf* PREDS2   = (bf*)(B0 + 33554432);      // [32,40)   written at ln (ENC22 dead)
  bf* DW2   = (bf*)(B0 + 50331648);         // [48,80)   split after y-combine
  bf* DBUF2 = (bf*)(B0 + 83886080);         // [80,96)   dec1 out (YF/Y2 dead)
  float* DECO = (float*)(B0);               // [0,32)    dec2 out (weights dead)

  stats_kernel<<<256, 256, 0, stream>>>(x_enc, MEAN, STD, RSTD);
  kfilt_kernel<<<8, 256, 0, stream>>>(mask_w, KF);
  xprep_kernel<<<256, 256, 0, stream>>>(x_enc, MEAN, RSTD, XNB);
  cmat_kernel<<<512, 256, 0, stream>>>(KF, CM);

  // conv as MFMA GEMM (A=CM hi-only, nseg=2): per nb [512,512] @ [8192,512]^T -> XIH scatter
  gemm_mfma<<<dim3(64, 4, 4), 256, 0, stream>>>(
      CM, 1024, 524288LL, 0LL, 0, XNB, 1024, 0LL, 0LL, 512,
      nullptr, 0, 0, nullptr, 0, 0, 0, nullptr, 0, 0, 0,
      XIH, 0, 0, 4194304LL, 0LL, 1, 512, 8192, 512, 2, 0, 1);

  // enc1: M=2048 N=1024 K=2048, A hi-only (nseg=2), relu, split-out
  split_kernel<<<8192, 256, 0, stream>>>(enc_w1, WW, 11);
  gemm_mfma<<<dim3(8, 16, 4), 256, 0, stream>>>(
      XIH, 2048, 4194304LL, 0LL, 0, WW, 4096, 4194304LL, 0LL, 2048,
      enc_b1, 1024LL, 0LL, nullptr, 0, 0, 0, nullptr, 0, 0, 0,
      ENCB2, 2048, 1024, 4194304LL, 0LL, 1, 2048, 1024, 2048, 2, 1, 0);

  split_kernel<<<2048, 256, 0, stream>>>(enc_w2, EW2, 10);
  split_kernel<<<1024, 256, 0, stream>>>(wxh, WXH2, 9);
  split_kernel<<<2048, 256, 0, stream>>>(dec_w1, DW1, 9);
  split_kernel<<<1024, 256, 0, stream>>>(whh, WSP, 9);
  tsplit_kernel<<<dim3(8, 8, 4), 256, 0, stream>>>(whh, WTSP);

  // enc2: M=2048 N=512 K=1024, nseg=3, split-out
  gemm_mfma<<<dim3(4, 16, 4), 256, 0, stream>>>(
      ENCB2, 2048, 4194304LL, 0LL, 1024, EW2, 2048, 1048576LL, 0LL, 1024,
      enc_b2, 512LL, 0LL, nullptr, 0, 0, 0, nullptr, 0, 0, 0,
      ENC22, 1024, 512, 2097152LL, 0LL, 1, 2048, 512, 1024, 3, 0, 0);

  // xp = enc2 @ wxh^T: fp32 out + XP2 hi|lo-concat (mode 2)
  gemm_mfma<<<dim3(4, 16, 4), 256, 0, stream>>>(
      ENC22, 1024, 2097152LL, 0LL, 512, WXH2, 1024, 524288LL, 0LL, 512,
      nullptr, 0, 0, nullptr, 0, 0, 0, XP, 512, 1048576LL, 0LL,
      XP2, 0, 0, 2097152LL, 0LL, 1, 2048, 512, 512, 3, 0, 2);

  // W2 = W @ W  (A=WSP, B=WTSP) -> split-out W2SP
  gemm_mfma<<<dim3(4, 4, 4), 256, 0, stream>>>(
      WSP, 1024, 524288LL, 0LL, 512, WTSP, 1024, 524288LL, 0LL, 512,
      nullptr, 0, 0, nullptr, 0, 0, 0, nullptr, 0, 0, 0,
      W2SP, 1024, 512, 524288LL, 0LL, 1, 512, 512, 512, 3, 0, 0);

  // y_j = xp_{2j} @ W^T + xp_{2j+1}   (z1 = j, z2 = nb, 16 total)
  gemm_mfma<<<dim3(4, 2, 16), 256, 0, stream>>>(
      XP2, 8192, 1024LL, 2097152LL, 4096, WSP, 1024, 0LL, 524288LL, 512,
      nullptr, 0, 0, XP + 512, 4096, 1024LL, 1048576LL,
      YF, 512, 524288LL, 131072LL,
      Y2, 1024, 512, 1048576LL, 262144LL, 4, 256, 512, 512, 3, 0, 0);

  // split dec_w2 now (XP/XP2 regions dead)
  split_kernel<<<8192, 256, 0, stream>>>(dec_w2, DW2, 10);

  // Horner with W2: h1 = y0@W2^T + y1; h2 = h1@W2^T + y2; h = h2@W2^T + y3
  gemm_mfma<<<dim3(4, 2, 4), 256, 0, stream>>>(
      Y2, 1024, 0LL, 262144LL, 512, W2SP, 1024, 0LL, 524288LL, 512,
      nullptr, 0, 0, YF + 524288, 512, 0LL, 131072LL, nullptr, 0, 0, 0,
      H2, 1024, 512, 0LL, 262144LL, 4, 256, 512, 512, 3, 0, 0);
  gemm_mfma<<<dim3(4, 2, 4), 256, 0, stream>>>(
      H2, 1024, 0LL, 262144LL, 512, W2SP, 1024, 0LL, 524288LL, 512,
      nullptr, 0, 0, YF + 1048576, 512, 0LL, 131072LL, nullptr, 0, 0, 0,
      H22, 1024, 512, 0LL, 262144LL, 4, 256, 512, 512, 3, 0, 0);
  gemm_mfma<<<dim3(4, 2, 4), 256, 0, stream>>>(
      H22, 1024, 0LL, 262144LL, 512, W2SP, 1024, 0LL, 524288LL, 512,
      nullptr, 0, 0, YF + 1572864, 512, 0LL, 131072LL, nullptr, 0, 0, 0,
      H2, 1024, 512, 0LL, 262144LL, 4, 256, 512, 512, 3, 0, 0);

  // free-run A: p1 = h@W^T (z1=0), p2 = h@W2^T (z1=1)
  gemm_mfma<<<dim3(4, 2, 8), 256, 0, stream>>>(
      H2, 1024, 0LL, 262144LL, 512, WSP, 1024, 2097152LL, 524288LL, 512,
      nullptr, 0, 0, nullptr, 0, 0, 0, PREDS, 2048, 512LL, 524288LL,
      P12, 1024, 512, 1048576LL, 262144LL, 4, 256, 512, 512, 3, 0, 0);
  // free-run B: p3 = p1@W2^T, p4 = p2@W2^T
  gemm_mfma<<<dim3(4, 2, 8), 256, 0, stream>>>(
      P12, 1024, 1048576LL, 262144LL, 512, W2SP, 1024, 0LL, 524288LL, 512,
      nullptr, 0, 0, nullptr, 0, 0, 0, PREDS + 1024, 2048, 512LL, 524288LL,
      nullptr, 0, 0, 0LL, 0LL, 4, 256, 512, 512, 3, 0, 0);

  ln_kernel<<<4096, 256, 0, stream>>>(PREDS, ln_g, ln_b, PREDS2);

  // dec1: M=1024 N=1024 K=512, nseg=3, relu, split-out
  gemm_mfma<<<dim3(8, 8, 4), 256, 0, stream>>>(
      PREDS2, 1024, 1048576LL, 0LL, 512, DW1, 1024, 1048576LL, 0LL, 512,
      dec_b1, 1024LL, 0LL, nullptr, 0, 0, 0, nullptr, 0, 0, 0,
      DBUF2, 2048, 1024, 2097152LL, 0LL, 1, 1024, 1024, 512, 3, 1, 0);
  // dec2: M=1024 N=2048 K=1024, nseg=3, fp32 out
  gemm_mfma<<<dim3(16, 8, 4), 256, 0, stream>>>(
      DBUF2, 2048, 2097152LL, 0LL, 1024, DW2, 2048, 4194304LL, 0LL, 1024,
      dec_b2, 2048LL, 0LL, nullptr, 0, 0, 0, DECO, 2048, 2097152LL, 0LL,
      nullptr, 0, 0, 0LL, 0LL, 1, 1024, 2048, 1024, 3, 0, 0);

  final_kernel<<<2048, 256, 0, stream>>>(DECO, MEAN, STD, out);
}

// Round 7
// 729.827 us; speedup vs baseline: 1.4938x; 1.2491x over previous
//
#include <hip/hip_runtime.h>
#include <hip/hip_bf16.h>
#include <math.h>

#define EPSF 1e-5f

typedef __attribute__((ext_vector_type(8))) short bf16x8;
typedef __attribute__((ext_vector_type(4))) float f32x4;

__device__ __forceinline__ void gld16(const void* g, void* l) {
  __builtin_amdgcn_global_load_lds(
      (const __attribute__((address_space(1))) unsigned int*)g,
      (__attribute__((address_space(3))) unsigned int*)l, 16, 0, 0);
}

// ---------------- instance-norm stats over time axis ----------------
__global__ __launch_bounds__(256) void stats_kernel(
    const float* __restrict__ x, float* __restrict__ meanp,
    float* __restrict__ stdp, float* __restrict__ rstdp)
{
  int b = blockIdx.x;
  int tid = threadIdx.x;
  int c = tid & 31, ls = tid >> 5;
  const float* xb = x + (size_t)b * 16384;
  float s = 0.f, s2 = 0.f;
  for (int l = ls; l < 512; l += 8) {
    float v = xb[l * 32 + c];
    s += v; s2 += v * v;
  }
  __shared__ float sb[8][32];
  __shared__ float sb2[8][32];
  sb[ls][c] = s; sb2[ls][c] = s2;
  __syncthreads();
  if (ls == 0) {
#pragma unroll
    for (int i = 1; i < 8; ++i) { s += sb[i][c]; s2 += sb2[i][c]; }
    float m = s * (1.f / 512.f);
    float var = s2 * (1.f / 512.f) - m * m;
    float sd = sqrtf(var + EPSF);
    meanp[b * 32 + c] = m;
    stdp[b * 32 + c] = sd;
    rstdp[b * 32 + c] = 1.f / sd;
  }
}

// ---------------- Fourier-mask -> time-domain filter taps (duplicated) ----------------
__global__ __launch_bounds__(256) void kfilt_kernel(
    const float* __restrict__ mw, float* __restrict__ kf)
{
  int gid = blockIdx.x * 256 + threadIdx.x;
  int nb = gid >> 9, t = gid & 511;
  const float* m = mw + nb * 257;
  float s0 = 1.f / (1.f + expf(-m[0]));
  float sN = 1.f / (1.f + expf(-m[256]));
  float acc = s0 + ((t & 1) ? -sN : sN);
  for (int f = 1; f < 256; ++f) {
    float sig = 1.f / (1.f + expf(-m[f]));
    int tf = (t * f) & 511;
    acc += 2.f * sig * cosf(6.28318530717958647f * (float)tf * (1.f / 512.f));
  }
  float kv = acc * (1.f / 512.f);
  kf[nb * 1024 + t] = kv;
  kf[nb * 1024 + t + 512] = kv;
}

// ---------------- x -> normalized, transposed, hi/lo split: XNB[b*32+c][l' | l'+512] ----------------
__global__ __launch_bounds__(256) void xprep_kernel(
    const float* __restrict__ x, const float* __restrict__ meanp,
    const float* __restrict__ rstdp, __hip_bfloat16* __restrict__ xnb)
{
  __shared__ float xs[512 * 33];
  int b = blockIdx.x, tid = threadIdx.x;
  const float* xb = x + (size_t)b * 16384;
#pragma unroll
  for (int i = 0; i < 16; ++i) {
    int idx4 = tid + i * 256;
    int l = idx4 >> 3, c0 = (idx4 & 7) * 4;
    float4 v = *(const float4*)(xb + idx4 * 4);
    xs[l * 33 + c0 + 0] = v.x;
    xs[l * 33 + c0 + 1] = v.y;
    xs[l * 33 + c0 + 2] = v.z;
    xs[l * 33 + c0 + 3] = v.w;
  }
  __syncthreads();
  for (int c = 0; c < 32; ++c) {
    float m = meanp[b * 32 + c];
    float r = rstdp[b * 32 + c];
    int l = tid * 2;
    float v0 = (xs[l * 33 + c] - m) * r;
    float v1 = (xs[(l + 1) * 33 + c] - m) * r;
    __hip_bfloat16 h0 = __float2bfloat16(v0);
    __hip_bfloat16 h1 = __float2bfloat16(v1);
    union { __hip_bfloat16 h[2]; unsigned int u; } H, L;
    H.h[0] = h0; H.h[1] = h1;
    L.h[0] = __float2bfloat16(v0 - __bfloat162float(h0));
    L.h[1] = __float2bfloat16(v1 - __bfloat162float(h1));
    unsigned int* dst =
        (unsigned int*)((unsigned short*)xnb + ((size_t)(b * 32 + c)) * 1024 + l);
    dst[0] = H.u;
    dst[256] = L.u;
  }
}

// ---------------- circulant matrix build: CM[nb][l][l' | l'+512] bf16 hi|lo ----------------
__global__ __launch_bounds__(256) void cmat_kernel(
    const float* __restrict__ kf, __hip_bfloat16* __restrict__ cm)
{
  int t = threadIdx.x;
  int row = blockIdx.x * 4 + (t >> 6);
  int nb = row >> 9, l = row & 511;
  int lp0 = (t & 63) * 8;
  union { __hip_bfloat16 h[8]; uint4 u; } H, L;
#pragma unroll
  for (int j = 0; j < 8; ++j) {
    float v = kf[nb * 1024 + 512 + l - (lp0 + j)];
    __hip_bfloat16 h = __float2bfloat16(v);
    H.h[j] = h;
    L.h[j] = __float2bfloat16(v - __bfloat162float(h));
  }
  unsigned short* dst = (unsigned short*)cm + (size_t)row * 1024 + lp0;
  *(uint4*)dst = H.u;
  *(uint4*)(dst + 512) = L.u;
}

// ---------------- fp32 -> bf16 hi/lo split: in [rows,K] -> out [rows,2K] ----------------
__global__ __launch_bounds__(256) void split_kernel(
    const float* __restrict__ in, __hip_bfloat16* __restrict__ out, int ks)
{
  int t = blockIdx.x * 256 + threadIdx.x;
  long long idx = (long long)t * 4;
  int K = 1 << ks;
  long long r = idx >> ks;
  int k = (int)(idx & (K - 1));
  float4 v = *(const float4*)(in + idx);
  float vv[4] = {v.x, v.y, v.z, v.w};
  union { __hip_bfloat16 h[4]; uint2 u; } H, L;
#pragma unroll
  for (int u = 0; u < 4; ++u) {
    H.h[u] = __float2bfloat16(vv[u]);
    L.h[u] = __float2bfloat16(vv[u] - __bfloat162float(H.h[u]));
  }
  unsigned short* ob = (unsigned short*)out + (r << (ks + 1)) + k;
  *(uint2*)ob = H.u;
  *(uint2*)(ob + K) = L.u;
}

// ---------------- transpose + split: WT2[nb][col][hi 512 | lo 512] = whh^T ----------------
__global__ __launch_bounds__(256) void tsplit_kernel(
    const float* __restrict__ w, __hip_bfloat16* __restrict__ wt2)
{
  __shared__ float ts[64][65];
  int bx = blockIdx.x, by = blockIdx.y, nb = blockIdx.z;
  int t = threadIdx.x;
  int tr = t >> 4, c0 = (t & 15) * 4;
  const float* wb = w + (size_t)nb * 262144;
#pragma unroll
  for (int k = 0; k < 4; ++k) {
    int r = tr + k * 16;
    float4 v = *(const float4*)(wb + (size_t)(by * 64 + r) * 512 + bx * 64 + c0);
    ts[r][c0 + 0] = v.x; ts[r][c0 + 1] = v.y;
    ts[r][c0 + 2] = v.z; ts[r][c0 + 3] = v.w;
  }
  __syncthreads();
  unsigned short* ob = (unsigned short*)wt2 + (size_t)nb * 524288;
#pragma unroll
  for (int k = 0; k < 4; ++k) {
    int r = tr + k * 16;
    float vv[4] = {ts[c0][r], ts[c0 + 1][r], ts[c0 + 2][r], ts[c0 + 3][r]};
    union { __hip_bfloat16 h[4]; uint2 u; } H, L;
#pragma unroll
    for (int j = 0; j < 4; ++j) {
      H.h[j] = __float2bfloat16(vv[j]);
      L.h[j] = __float2bfloat16(vv[j] - __bfloat162float(H.h[j]));
    }
    size_t row = (size_t)(bx * 64 + r);
    *(uint2*)(ob + row * 1024 + by * 64 + c0) = H.u;
    *(uint2*)(ob + row * 1024 + 512 + by * 64 + c0) = L.u;
  }
}

// ---------------- split-bf16 MFMA GEMM, fused-segment K-loop, tiled by template ----------------
// Tile = (32*NI) x (32*NJ), 256 thr (4 waves, 2x2). BK=32, 16x16x32 bf16 MFMA.
// nseg3: acc += Ahi*Bhi + Ahi*Blo + Alo*Bhi     nseg2: acc += Ahi*Bhi + Ahi*Blo
// z-batching two-level: off = (bz/nz2)*b?1 + (bz%nz2)*b?2 (element units).
// mode 0: normal epilogue (bias, Add fp32, relu, Cf fp32, C2 hi at ldc2 [+lo at loC2 if loC2!=0])
// mode 1: XIH scatter (conv output, hi only)
// mode 2: Cf normal + C2 as XP concat [b][f*512+n | 4096+f*512+n]
template<int NI, int NJ>
__global__ __launch_bounds__(256) void gemm_mfma(
    const __hip_bfloat16* __restrict__ A_, int ldA, long long bA1, long long bA2, int loA,
    const __hip_bfloat16* __restrict__ B_, int ldB, long long bB1, long long bB2, int loB,
    const float* __restrict__ bias, long long bBias1, long long bBias2,
    const float* __restrict__ Add, int ldadd, long long bAdd1, long long bAdd2,
    float* __restrict__ Cf, int ldcf, long long bCf1, long long bCf2,
    __hip_bfloat16* __restrict__ C2, int ldc2, int loC2, long long bC21, long long bC22,
    int nz2, int M, int N, int K, int nseg, int relu, int mode)
{
  __shared__ short sAh[32 * NI * 32];
  __shared__ short sAl[32 * NI * 32];
  __shared__ short sBh[32 * NJ * 32];
  __shared__ short sBl[32 * NJ * 32];
  int z1 = blockIdx.z / nz2, z2 = blockIdx.z % nz2;
  const short* Ab = (const short*)A_ + (long long)z1 * bA1 + (long long)z2 * bA2;
  const short* Bb = (const short*)B_ + (long long)z1 * bB1 + (long long)z2 * bB2;
  int tid = threadIdx.x, wave = tid >> 6, lane = tid & 63;
  int bm = blockIdx.y * (32 * NI), bn = blockIdx.x * (32 * NJ);
  int wrow = (wave >> 1) * (16 * NI), wcol = (wave & 1) * (16 * NJ);

  int sr = lane >> 2;
  int qg = (lane & 3) ^ (sr & 3);
  int arA = wave * 8 * NI;           // A rows staged by this wave
  int arB = wave * 8 * NJ;           // B rows staged by this wave

  f32x4 acc[NI][NJ];
#pragma unroll
  for (int i = 0; i < NI; ++i)
#pragma unroll
    for (int j = 0; j < NJ; ++j)
      acc[i][j] = (f32x4){0.f, 0.f, 0.f, 0.f};

  int frow = lane & 15;
  int fq = lane >> 4;
  int aoffs[NI], boffs[NJ];
#pragma unroll
  for (int i = 0; i < NI; ++i) {
    int ra = wrow + 16 * i + frow;
    aoffs[i] = ra * 32 + ((fq ^ (ra & 3)) << 3);
  }
#pragma unroll
  for (int j = 0; j < NJ; ++j) {
    int rb = wcol + 16 * j + frow;
    boffs[j] = rb * 32 + ((fq ^ (rb & 3)) << 3);
  }

  const short* Ah = Ab + (long long)(bm + arA + sr) * ldA + qg * 8;
  const short* Al = Ah + loA;
  const short* Bh = Bb + (long long)(bn + arB + sr) * ldB + qg * 8;
  const short* Bl = Bh + loB;
  int three = (nseg == 3);

  for (int ko = 0; ko < K; ko += 32) {
#pragma unroll
    for (int cc = 0; cc < NI / 2; ++cc) {
      gld16(Ah + ko + cc * 16 * ldA, &sAh[(arA + cc * 16) * 32]);
      if (three)
        gld16(Al + ko + cc * 16 * ldA, &sAl[(arA + cc * 16) * 32]);
    }
#pragma unroll
    for (int cc = 0; cc < NJ / 2; ++cc) {
      gld16(Bh + ko + cc * 16 * ldB, &sBh[(arB + cc * 16) * 32]);
      gld16(Bl + ko + cc * 16 * ldB, &sBl[(arB + cc * 16) * 32]);
    }
    __syncthreads();
    bf16x8 ah[NI], al[NI], bh[NJ], bl[NJ];
#pragma unroll
    for (int i = 0; i < NI; ++i) ah[i] = *(const bf16x8*)&sAh[aoffs[i]];
#pragma unroll
    for (int j = 0; j < NJ; ++j) bh[j] = *(const bf16x8*)&sBh[boffs[j]];
#pragma unroll
    for (int j = 0; j < NJ; ++j) bl[j] = *(const bf16x8*)&sBl[boffs[j]];
    if (three) {
#pragma unroll
      for (int i = 0; i < NI; ++i) al[i] = *(const bf16x8*)&sAl[aoffs[i]];
    }
#pragma unroll
    for (int i = 0; i < NI; ++i)
#pragma unroll
      for (int j = 0; j < NJ; ++j) {
        acc[i][j] = __builtin_amdgcn_mfma_f32_16x16x32_bf16(ah[i], bh[j], acc[i][j], 0, 0, 0);
        acc[i][j] = __builtin_amdgcn_mfma_f32_16x16x32_bf16(ah[i], bl[j], acc[i][j], 0, 0, 0);
        if (three)
          acc[i][j] = __builtin_amdgcn_mfma_f32_16x16x32_bf16(al[i], bh[j], acc[i][j], 0, 0, 0);
      }
    __syncthreads();
  }

  short* c2z = C2 ? (short*)C2 + (long long)z1 * bC21 + (long long)z2 * bC22 : nullptr;

  if (mode == 1) {
    // m = l (0..511), n = b*32+c -> XIH row = b*8 + l/64, col = (l%64)*32 + c
#pragma unroll
    for (int j = 0; j < NJ; ++j) {
      int n = bn + wcol + 16 * j + frow;
      int bidx = n >> 5, c = n & 31;
#pragma unroll
      for (int i = 0; i < NI; ++i)
#pragma unroll
        for (int r = 0; r < 4; ++r) {
          int m = bm + wrow + 16 * i + fq * 4 + r;
          int row = bidx * 8 + (m >> 6);
          int col = (m & 63) * 32 + c;
          ((__hip_bfloat16*)c2z)[(long long)row * 2048 + col] =
              __float2bfloat16(acc[i][j][r]);
        }
    }
    return;
  }

  const float* biasz = bias ? bias + (long long)z1 * bBias1 + (long long)z2 * bBias2 : nullptr;
  const float* addz  = Add  ? Add  + (long long)z1 * bAdd1  + (long long)z2 * bAdd2  : nullptr;
  float* cfz = Cf ? Cf + (long long)z1 * bCf1 + (long long)z2 * bCf2 : nullptr;

#pragma unroll
  for (int j = 0; j < NJ; ++j) {
    int n = bn + wcol + 16 * j + frow;
    float bv = biasz ? biasz[n] : 0.f;
#pragma unroll
    for (int i = 0; i < NI; ++i) {
#pragma unroll
      for (int r = 0; r < 4; ++r) {
        int m = bm + wrow + 16 * i + fq * 4 + r;
        float v = acc[i][j][r] + bv;
        if (addz) v += addz[(long long)m * ldadd + n];
        if (relu) v = fmaxf(v, 0.f);
        if (cfz) cfz[(long long)m * ldcf + n] = v;
        if (c2z) {
          __hip_bfloat16 h = __float2bfloat16(v);
          if (mode == 2) {
            __hip_bfloat16 l = __float2bfloat16(v - __bfloat162float(h));
            long long off = (long long)(m >> 3) * 8192 + (m & 7) * 512 + n;
            ((__hip_bfloat16*)c2z)[off] = h;
            ((__hip_bfloat16*)c2z)[off + 4096] = l;
          } else {
            ((__hip_bfloat16*)c2z)[(long long)m * ldc2 + n] = h;
            if (loC2) {
              __hip_bfloat16 l = __float2bfloat16(v - __bfloat162float(h));
              ((__hip_bfloat16*)c2z)[(long long)m * ldc2 + loC2 + n] = l;
            }
          }
        }
      }
    }
  }
}

// ---------------- LayerNorm over 512, writes bf16 hi-only [row, 512] ----------------
__global__ __launch_bounds__(256) void ln_kernel(
    const float* __restrict__ p, const float* __restrict__ g,
    const float* __restrict__ bb, __hip_bfloat16* __restrict__ p2)
{
  int row = blockIdx.x;              // NB*B*4 = 4096
  int nb = row >> 10;
  const float* pr = p + (size_t)row * 512;
  int tid = threadIdx.x;
  float v0 = pr[tid], v1 = pr[tid + 256];
  float s = v0 + v1, s2 = v0 * v0 + v1 * v1;
#pragma unroll
  for (int o = 32; o > 0; o >>= 1) {
    s += __shfl_down(s, o);
    s2 += __shfl_down(s2, o);
  }
  __shared__ float rs[4];
  __shared__ float rs2[4];
  int w = tid >> 6;
  if ((tid & 63) == 0) { rs[w] = s; rs2[w] = s2; }
  __syncthreads();
  s = rs[0] + rs[1] + rs[2] + rs[3];
  s2 = rs2[0] + rs2[1] + rs2[2] + rs2[3];
  float mval = s * (1.f / 512.f);
  float var = s2 * (1.f / 512.f) - mval * mval;
  float r = 1.f / sqrtf(var + EPSF);
  const float* gn = g + nb * 512;
  const float* bn = bb + nb * 512;
  float y0 = (v0 - mval) * r * gn[tid] + bn[tid];
  float y1 = (v1 - mval) * r * gn[tid + 256] + bn[tid + 256];
  __hip_bfloat16* o2 = p2 + (size_t)nb * 524288 + (size_t)(row & 1023) * 512;
  o2[tid] = __float2bfloat16(y0);
  o2[tid + 256] = __float2bfloat16(y1);
}

// ---------------- final: out = (sum_nb deco) * std + mean ----------------
__global__ __launch_bounds__(256) void final_kernel(
    const float* __restrict__ deco, const float* __restrict__ meanp,
    const float* __restrict__ stdp, float* __restrict__ out)
{
  int t = blockIdx.x * 256 + threadIdx.x;
  int b = t >> 11;
  int r = t & 2047;
  int p = (r >> 3) & 63;
  int cq = r & 7;
  size_t base = ((size_t)(b * 4 + (r >> 9))) * 2048 + p * 32 + cq * 4;
  const size_t nbs = 1024ull * 2048ull;
  float4 a0 = *(const float4*)(deco + base);
  float4 a1 = *(const float4*)(deco + nbs + base);
  float4 a2 = *(const float4*)(deco + 2 * nbs + base);
  float4 a3 = *(const float4*)(deco + 3 * nbs + base);
  float4 m4 = *(const float4*)(meanp + b * 32 + cq * 4);
  float4 s4 = *(const float4*)(stdp + b * 32 + cq * 4);
  float4 o;
  o.x = (a0.x + a1.x + a2.x + a3.x) * s4.x + m4.x;
  o.y = (a0.y + a1.y + a2.y + a3.y) * s4.y + m4.y;
  o.z = (a0.z + a1.z + a2.z + a3.z) * s4.z + m4.z;
  o.w = (a0.w + a1.w + a2.w + a3.w) * s4.w + m4.w;
  *(float4*)(out + (size_t)t * 4) = o;
}

extern "C" void kernel_launch(void* const* d_in, const int* in_sizes, int n_in,
                              void* d_out, int out_size, void* d_ws, size_t ws_size,
                              hipStream_t stream) {
  const float* x_enc  = (const float*)d_in[0];
  const float* mask_w = (const float*)d_in[4];
  const float* enc_w1 = (const float*)d_in[5];
  const float* enc_b1 = (const float*)d_in[6];
  const float* enc_w2 = (const float*)d_in[7];
  const float* enc_b2 = (const float*)d_in[8];
  const float* wxh    = (const float*)d_in[9];
  const float* whh    = (const float*)d_in[10];
  const float* ln_g   = (const float*)d_in[11];
  const float* ln_b   = (const float*)d_in[12];
  const float* dec_w1 = (const float*)d_in[13];
  const float* dec_b1 = (const float*)d_in[14];
  const float* dec_w2 = (const float*)d_in[15];
  const float* dec_b2 = (const float*)d_in[16];
  float* out = (float*)d_out;

  typedef __hip_bfloat16 bf;
  char* W = (char*)d_ws;
  float* MEAN = (float*)(W);
  float* STD  = (float*)(W + 32768);
  float* RSTD = (float*)(W + 65536);
  float* KF   = (float*)(W + 98304);
  char* B0 = W + 131072;
  // ---- layout (MB offsets from B0); hi-only activations shrink several buffers ----
  bf* XIH   = (bf*)(B0);                    // [0,32)
  bf* XNB   = (bf*)(B0 + 33554432);         // [32,48)   dead after conv
  bf* CM    = (bf*)(B0 + 50331648);         // [48,52)   dead after conv
  bf* WW    = (bf*)(B0 + 33554432);         // [32,64)   written after conv, dead after enc1
  bf* ENCB2 = (bf*)(B0 + 67108864);         // [64,80)   hi-only 16MB, dead after enc2
  bf* EW2   = (bf*)(B0);                    // [0,8)
  bf* WXH2  = (bf*)(B0 + 8388608);          // [8,12)
  bf* DW1   = (bf*)(B0 + 12582912);         // [12,20)   read at dec1
  bf* WSP   = (bf*)(B0 + 20971520);         // [20,24)
  bf* W2SP  = (bf*)(B0 + 25165824);         // [24,28)
  bf* WTSP  = (bf*)(B0 + 29360128);         // [28,32)
  bf* ENC22 = (bf*)(B0 + 33554432);         // [32,40)   hi-only 8MB, dead after xp
  float* XP = (float*)(B0 + 50331648);      // [48,64)   dead after y-combine
  bf* XP2   = (bf*)(B0 + 67108864);         // [64,80)   hi|lo, dead after y-combine (ENCB2 dead)
  float* YF = (float*)(B0 + 83886080);      // [80,88)   dead after Horner-3
  bf* Y2    = (bf*)(B0 + 92274688);         // [88,96)   hi|lo, dead after Horner-1
  bf* H2    = (bf*)(B0 + 100663296);        // [96,98)
  bf* H22   = (bf*)(B0 + 102760448);        // [98,100)
  bf* P12   = (bf*)(B0 + 104857600);        // [100,104)
  float* PREDS = (float*)(B0 + 109051904);  // [104,112)
  bf* PREDS2   = (bf*)(B0 + 33554432);      // [32,36)   hi-only 4MB, written at ln
  bf* DW2   = (bf*)(B0 + 50331648);         // [48,80)   split after y-combine
  bf* DBUF2 = (bf*)(B0 + 83886080);         // [80,88)   hi-only 8MB, dec1 out (YF dead)
  float* DECO = (float*)(B0);               // [0,32)    dec2 out (weights dead)

  stats_kernel<<<256, 256, 0, stream>>>(x_enc, MEAN, STD, RSTD);
  kfilt_kernel<<<8, 256, 0, stream>>>(mask_w, KF);
  xprep_kernel<<<256, 256, 0, stream>>>(x_enc, MEAN, RSTD, XNB);
  cmat_kernel<<<512, 256, 0, stream>>>(KF, CM);

  // conv as MFMA GEMM (A=CM hi-only, nseg=2): per nb [512,512] @ [8192,512]^T -> XIH scatter
  gemm_mfma<4, 4><<<dim3(64, 4, 4), 256, 0, stream>>>(
      CM, 1024, 524288LL, 0LL, 0, XNB, 1024, 0LL, 0LL, 512,
      nullptr, 0, 0, nullptr, 0, 0, 0, nullptr, 0, 0, 0,
      XIH, 0, 0, 4194304LL, 0LL, 1, 512, 8192, 512, 2, 0, 1);

  // enc1: M=2048 N=1024 K=2048, A hi-only (nseg=2), relu, hi-only out
  split_kernel<<<8192, 256, 0, stream>>>(enc_w1, WW, 11);
  gemm_mfma<4, 2><<<dim3(16, 16, 4), 256, 0, stream>>>(
      XIH, 2048, 4194304LL, 0LL, 0, WW, 4096, 4194304LL, 0LL, 2048,
      enc_b1, 1024LL, 0LL, nullptr, 0, 0, 0, nullptr, 0, 0, 0,
      ENCB2, 1024, 0, 2097152LL, 0LL, 1, 2048, 1024, 2048, 2, 1, 0);

  split_kernel<<<2048, 256, 0, stream>>>(enc_w2, EW2, 10);
  split_kernel<<<1024, 256, 0, stream>>>(wxh, WXH2, 9);
  split_kernel<<<2048, 256, 0, stream>>>(dec_w1, DW1, 9);
  split_kernel<<<1024, 256, 0, stream>>>(whh, WSP, 9);
  tsplit_kernel<<<dim3(8, 8, 4), 256, 0, stream>>>(whh, WTSP);

  // enc2: M=2048 N=512 K=1024, A hi-only nseg=2, hi-only out
  gemm_mfma<4, 2><<<dim3(8, 16, 4), 256, 0, stream>>>(
      ENCB2, 1024, 2097152LL, 0LL, 0, EW2, 2048, 1048576LL, 0LL, 1024,
      enc_b2, 512LL, 0LL, nullptr, 0, 0, 0, nullptr, 0, 0, 0,
      ENC22, 512, 0, 1048576LL, 0LL, 1, 2048, 512, 1024, 2, 0, 0);

  // xp = enc2 @ wxh^T: A hi-only nseg=2; fp32 out + XP2 hi|lo-concat (mode 2)
  gemm_mfma<4, 2><<<dim3(8, 16, 4), 256, 0, stream>>>(
      ENC22, 512, 1048576LL, 0LL, 0, WXH2, 1024, 524288LL, 0LL, 512,
      nullptr, 0, 0, nullptr, 0, 0, 0, XP, 512, 1048576LL, 0LL,
      XP2, 0, 0, 2097152LL, 0LL, 1, 2048, 512, 512, 2, 0, 2);

  // W2 = W @ W  (nseg=3) -> split-out W2SP
  gemm_mfma<2, 2><<<dim3(8, 8, 4), 256, 0, stream>>>(
      WSP, 1024, 524288LL, 0LL, 512, WTSP, 1024, 524288LL, 0LL, 512,
      nullptr, 0, 0, nullptr, 0, 0, 0, nullptr, 0, 0, 0,
      W2SP, 1024, 512, 524288LL, 0LL, 1, 512, 512, 512, 3, 0, 0);

  // y_j = xp_{2j} @ W^T + xp_{2j+1}   (z1 = j, z2 = nb, 16 total), nseg=3
  gemm_mfma<2, 2><<<dim3(8, 4, 16), 256, 0, stream>>>(
      XP2, 8192, 1024LL, 2097152LL, 4096, WSP, 1024, 0LL, 524288LL, 512,
      nullptr, 0, 0, XP + 512, 4096, 1024LL, 1048576LL,
      YF, 512, 524288LL, 131072LL,
      Y2, 1024, 512, 1048576LL, 262144LL, 4, 256, 512, 512, 3, 0, 0);

  // split dec_w2 now (XP/XP2 regions dead)
  split_kernel<<<8192, 256, 0, stream>>>(dec_w2, DW2, 10);

  // Horner with W2 (nseg=3): h1 = y0@W2^T + y1; h2 = h1@W2^T + y2; h = h2@W2^T + y3
  gemm_mfma<2, 2><<<dim3(8, 4, 4), 256, 0, stream>>>(
      Y2, 1024, 0LL, 262144LL, 512, W2SP, 1024, 0LL, 524288LL, 512,
      nullptr, 0, 0, YF + 524288, 512, 0LL, 131072LL, nullptr, 0, 0, 0,
      H2, 1024, 512, 0LL, 262144LL, 4, 256, 512, 512, 3, 0, 0);
  gemm_mfma<2, 2><<<dim3(8, 4, 4), 256, 0, stream>>>(
      H2, 1024, 0LL, 262144LL, 512, W2SP, 1024, 0LL, 524288LL, 512,
      nullptr, 0, 0, YF + 1048576, 512, 0LL, 131072LL, nullptr, 0, 0, 0,
      H22, 1024, 512, 0LL, 262144LL, 4, 256, 512, 512, 3, 0, 0);
  gemm_mfma<2, 2><<<dim3(8, 4, 4), 256, 0, stream>>>(
      H22, 1024, 0LL, 262144LL, 512, W2SP, 1024, 0LL, 524288LL, 512,
      nullptr, 0, 0, YF + 1572864, 512, 0LL, 131072LL, nullptr, 0, 0, 0,
      H2, 1024, 512, 0LL, 262144LL, 4, 256, 512, 512, 3, 0, 0);

  // free-run A: p1 = h@W^T (z1=0), p2 = h@W2^T (z1=1), nseg=3
  gemm_mfma<2, 2><<<dim3(8, 4, 8), 256, 0, stream>>>(
      H2, 1024, 0LL, 262144LL, 512, WSP, 1024, 2097152LL, 524288LL, 512,
      nullptr, 0, 0, nullptr, 0, 0, 0, PREDS, 2048, 512LL, 524288LL,
      P12, 1024, 512, 1048576LL, 262144LL, 4, 256, 512, 512, 3, 0, 0);
  // free-run B: p3 = p1@W2^T, p4 = p2@W2^T, nseg=3
  gemm_mfma<2, 2><<<dim3(8, 4, 8), 256, 0, stream>>>(
      P12, 1024, 1048576LL, 262144LL, 512, W2SP, 1024, 0LL, 524288LL, 512,
      nullptr, 0, 0, nullptr, 0, 0, 0, PREDS + 1024, 2048, 512LL, 524288LL,
      nullptr, 0, 0, 0LL, 0LL, 4, 256, 512, 512, 3, 0, 0);

  ln_kernel<<<4096, 256, 0, stream>>>(PREDS, ln_g, ln_b, PREDS2);

  // dec1: M=1024 N=1024 K=512, A hi-only nseg=2, relu, hi-only out
  gemm_mfma<4, 2><<<dim3(16, 8, 4), 256, 0, stream>>>(
      PREDS2, 512, 524288LL, 0LL, 0, DW1, 1024, 1048576LL, 0LL, 512,
      dec_b1, 1024LL, 0LL, nullptr, 0, 0, 0, nullptr, 0, 0, 0,
      DBUF2, 1024, 0, 1048576LL, 0LL, 1, 1024, 1024, 512, 2, 1, 0);
  // dec2: M=1024 N=2048 K=1024, A hi-only nseg=2, fp32 out
  gemm_mfma<4, 2><<<dim3(32, 8, 4), 256, 0, stream>>>(
      DBUF2, 1024, 1048576LL, 0LL, 0, DW2, 2048, 4194304LL, 0LL, 1024,
      dec_b2, 2048LL, 0LL, nullptr, 0, 0, 0, DECO, 2048, 2097152LL, 0LL,
      nullptr, 0, 0, 0LL, 0LL, 1, 1024, 2048, 1024, 2, 0, 0);

  final_kernel<<<2048, 256, 0, stream>>>(DECO, MEAN, STD, out);
}

// Round 9
// 612.041 us; speedup vs baseline: 1.7812x; 1.1924x over previous
//
#include <hip/hip_runtime.h>
#include <hip/hip_bf16.h>
#include <math.h>

#define EPSF 1e-5f

typedef __attribute__((ext_vector_type(8))) short bf16x8;
typedef __attribute__((ext_vector_type(4))) float f32x4;

__device__ __forceinline__ void gld16(const void* g, void* l) {
  __builtin_amdgcn_global_load_lds(
      (const __attribute__((address_space(1))) unsigned int*)g,
      (__attribute__((address_space(3))) unsigned int*)l, 16, 0, 0);
}

// ---------------- instance-norm stats over time axis ----------------
__global__ __launch_bounds__(256) void stats_kernel(
    const float* __restrict__ x, float* __restrict__ meanp,
    float* __restrict__ stdp, float* __restrict__ rstdp)
{
  int b = blockIdx.x;
  int tid = threadIdx.x;
  int c = tid & 31, ls = tid >> 5;
  const float* xb = x + (size_t)b * 16384;
  float s = 0.f, s2 = 0.f;
  for (int l = ls; l < 512; l += 8) {
    float v = xb[l * 32 + c];
    s += v; s2 += v * v;
  }
  __shared__ float sb[8][32];
  __shared__ float sb2[8][32];
  sb[ls][c] = s; sb2[ls][c] = s2;
  __syncthreads();
  if (ls == 0) {
#pragma unroll
    for (int i = 1; i < 8; ++i) { s += sb[i][c]; s2 += sb2[i][c]; }
    float m = s * (1.f / 512.f);
    float var = s2 * (1.f / 512.f) - m * m;
    float sd = sqrtf(var + EPSF);
    meanp[b * 32 + c] = m;
    stdp[b * 32 + c] = sd;
    rstdp[b * 32 + c] = 1.f / sd;
  }
}

// ---------------- Fourier-mask -> time-domain filter taps (duplicated) ----------------
__global__ __launch_bounds__(256) void kfilt_kernel(
    const float* __restrict__ mw, float* __restrict__ kf)
{
  int gid = blockIdx.x * 256 + threadIdx.x;
  int nb = gid >> 9, t = gid & 511;
  const float* m = mw + nb * 257;
  float s0 = 1.f / (1.f + expf(-m[0]));
  float sN = 1.f / (1.f + expf(-m[256]));
  float acc = s0 + ((t & 1) ? -sN : sN);
  for (int f = 1; f < 256; ++f) {
    float sig = 1.f / (1.f + expf(-m[f]));
    int tf = (t * f) & 511;
    acc += 2.f * sig * cosf(6.28318530717958647f * (float)tf * (1.f / 512.f));
  }
  float kv = acc * (1.f / 512.f);
  kf[nb * 1024 + t] = kv;
  kf[nb * 1024 + t + 512] = kv;
}

// ---------------- x -> normalized, transposed, hi/lo split: XNB[b*32+c][l' | l'+512] ----------------
__global__ __launch_bounds__(256) void xprep_kernel(
    const float* __restrict__ x, const float* __restrict__ meanp,
    const float* __restrict__ rstdp, __hip_bfloat16* __restrict__ xnb)
{
  __shared__ float xs[512 * 33];
  int b = blockIdx.x, tid = threadIdx.x;
  const float* xb = x + (size_t)b * 16384;
#pragma unroll
  for (int i = 0; i < 16; ++i) {
    int idx4 = tid + i * 256;
    int l = idx4 >> 3, c0 = (idx4 & 7) * 4;
    float4 v = *(const float4*)(xb + idx4 * 4);
    xs[l * 33 + c0 + 0] = v.x;
    xs[l * 33 + c0 + 1] = v.y;
    xs[l * 33 + c0 + 2] = v.z;
    xs[l * 33 + c0 + 3] = v.w;
  }
  __syncthreads();
  for (int c = 0; c < 32; ++c) {
    float m = meanp[b * 32 + c];
    float r = rstdp[b * 32 + c];
    int l = tid * 2;
    float v0 = (xs[l * 33 + c] - m) * r;
    float v1 = (xs[(l + 1) * 33 + c] - m) * r;
    __hip_bfloat16 h0 = __float2bfloat16(v0);
    __hip_bfloat16 h1 = __float2bfloat16(v1);
    union { __hip_bfloat16 h[2]; unsigned int u; } H, L;
    H.h[0] = h0; H.h[1] = h1;
    L.h[0] = __float2bfloat16(v0 - __bfloat162float(h0));
    L.h[1] = __float2bfloat16(v1 - __bfloat162float(h1));
    unsigned int* dst =
        (unsigned int*)((unsigned short*)xnb + ((size_t)(b * 32 + c)) * 1024 + l);
    dst[0] = H.u;
    dst[256] = L.u;
  }
}

// ---------------- circulant matrix build: CM[nb][l][l' | l'+512] bf16 hi|lo ----------------
__global__ __launch_bounds__(256) void cmat_kernel(
    const float* __restrict__ kf, __hip_bfloat16* __restrict__ cm)
{
  int t = threadIdx.x;
  int row = blockIdx.x * 4 + (t >> 6);
  int nb = row >> 9, l = row & 511;
  int lp0 = (t & 63) * 8;
  union { __hip_bfloat16 h[8]; uint4 u; } H, L;
#pragma unroll
  for (int j = 0; j < 8; ++j) {
    float v = kf[nb * 1024 + 512 + l - (lp0 + j)];
    __hip_bfloat16 h = __float2bfloat16(v);
    H.h[j] = h;
    L.h[j] = __float2bfloat16(v - __bfloat162float(h));
  }
  unsigned short* dst = (unsigned short*)cm + (size_t)row * 1024 + lp0;
  *(uint4*)dst = H.u;
  *(uint4*)(dst + 512) = L.u;
}

// ---------------- fp32 -> bf16 hi/lo split: in [rows,K] -> out [rows,2K] ----------------
__global__ __launch_bounds__(256) void split_kernel(
    const float* __restrict__ in, __hip_bfloat16* __restrict__ out, int ks)
{
  int t = blockIdx.x * 256 + threadIdx.x;
  long long idx = (long long)t * 4;
  int K = 1 << ks;
  long long r = idx >> ks;
  int k = (int)(idx & (K - 1));
  float4 v = *(const float4*)(in + idx);
  float vv[4] = {v.x, v.y, v.z, v.w};
  union { __hip_bfloat16 h[4]; uint2 u; } H, L;
#pragma unroll
  for (int u = 0; u < 4; ++u) {
    H.h[u] = __float2bfloat16(vv[u]);
    L.h[u] = __float2bfloat16(vv[u] - __bfloat162float(H.h[u]));
  }
  unsigned short* ob = (unsigned short*)out + (r << (ks + 1)) + k;
  *(uint2*)ob = H.u;
  *(uint2*)(ob + K) = L.u;
}

// ---------------- fp32 -> bf16 hi-only cast (dense) ----------------
__global__ __launch_bounds__(256) void splith_kernel(
    const float* __restrict__ in, __hip_bfloat16* __restrict__ out)
{
  long long idx = ((long long)blockIdx.x * 256 + threadIdx.x) * 4;
  float4 v = *(const float4*)(in + idx);
  union { __hip_bfloat16 h[4]; uint2 u; } H;
  H.h[0] = __float2bfloat16(v.x);
  H.h[1] = __float2bfloat16(v.y);
  H.h[2] = __float2bfloat16(v.z);
  H.h[3] = __float2bfloat16(v.w);
  *(uint2*)((unsigned short*)out + idx) = H.u;
}

// ---------------- transpose + split: WT2[nb][col][hi 512 | lo 512] = whh^T ----------------
__global__ __launch_bounds__(256) void tsplit_kernel(
    const float* __restrict__ w, __hip_bfloat16* __restrict__ wt2)
{
  __shared__ float ts[64][65];
  int bx = blockIdx.x, by = blockIdx.y, nb = blockIdx.z;
  int t = threadIdx.x;
  int tr = t >> 4, c0 = (t & 15) * 4;
  const float* wb = w + (size_t)nb * 262144;
#pragma unroll
  for (int k = 0; k < 4; ++k) {
    int r = tr + k * 16;
    float4 v = *(const float4*)(wb + (size_t)(by * 64 + r) * 512 + bx * 64 + c0);
    ts[r][c0 + 0] = v.x; ts[r][c0 + 1] = v.y;
    ts[r][c0 + 2] = v.z; ts[r][c0 + 3] = v.w;
  }
  __syncthreads();
  unsigned short* ob = (unsigned short*)wt2 + (size_t)nb * 524288;
#pragma unroll
  for (int k = 0; k < 4; ++k) {
    int r = tr + k * 16;
    float vv[4] = {ts[c0][r], ts[c0 + 1][r], ts[c0 + 2][r], ts[c0 + 3][r]};
    union { __hip_bfloat16 h[4]; uint2 u; } H, L;
#pragma unroll
    for (int j = 0; j < 4; ++j) {
      H.h[j] = __float2bfloat16(vv[j]);
      L.h[j] = __float2bfloat16(vv[j] - __bfloat162float(H.h[j]));
    }
    size_t row = (size_t)(bx * 64 + r);
    *(uint2*)(ob + row * 1024 + by * 64 + c0) = H.u;
    *(uint2*)(ob + row * 1024 + 512 + by * 64 + c0) = L.u;
  }
}

// ---------------- split-bf16 MFMA GEMM, fused-segment K-loop, tiled by template ----------------
// Tile = (32*NI) x (32*NJ), 256 thr (4 waves, 2x2). BK=32, 16x16x32 bf16 MFMA.
// nseg1: Ahi*Bhi   nseg2: Ahi*(Bhi+Blo)   nseg3: + Alo*Bhi
// swapg=1: blockIdx.x indexes M-tiles (XCD-local A stripes)
// z-batching two-level: off = (bz/nz2)*b?1 + (bz%nz2)*b?2 (element units).
// mode 0: normal epilogue (bias, Add fp32, relu, Cf fp32, C2 hi at ldc2 [+lo at loC2 if !=0])
// mode 1: XIH scatter (conv output, hi only)
// mode 2: Cf normal + C2 as XP concat [b][f*512+n | 4096+f*512+n]
template<int NI, int NJ>
__global__ __launch_bounds__(256) void gemm_mfma(
    const __hip_bfloat16* __restrict__ A_, int ldA, long long bA1, long long bA2, int loA,
    const __hip_bfloat16* __restrict__ B_, int ldB, long long bB1, long long bB2, int loB,
    const float* __restrict__ bias, long long bBias1, long long bBias2,
    const float* __restrict__ Add, int ldadd, long long bAdd1, long long bAdd2,
    float* __restrict__ Cf, int ldcf, long long bCf1, long long bCf2,
    __hip_bfloat16* __restrict__ C2, int ldc2, int loC2, long long bC21, long long bC22,
    int nz2, int M, int N, int K, int nseg, int relu, int mode, int swapg)
{
  __shared__ short sAh[32 * NI * 32];
  __shared__ short sAl[32 * NI * 32];
  __shared__ short sBh[32 * NJ * 32];
  __shared__ short sBl[32 * NJ * 32];
  int z1 = blockIdx.z / nz2, z2 = blockIdx.z % nz2;
  const short* Ab = (const short*)A_ + (long long)z1 * bA1 + (long long)z2 * bA2;
  const short* Bb = (const short*)B_ + (long long)z1 * bB1 + (long long)z2 * bB2;
  int tid = threadIdx.x, wave = tid >> 6, lane = tid & 63;
  int bxv = swapg ? blockIdx.y : blockIdx.x;
  int byv = swapg ? blockIdx.x : blockIdx.y;
  int bm = byv * (32 * NI), bn = bxv * (32 * NJ);
  int wrow = (wave >> 1) * (16 * NI), wcol = (wave & 1) * (16 * NJ);

  int sr = lane >> 2;
  int qg = (lane & 3) ^ (sr & 3);
  int arA = wave * 8 * NI;
  int arB = wave * 8 * NJ;

  f32x4 acc[NI][NJ];
#pragma unroll
  for (int i = 0; i < NI; ++i)
#pragma unroll
    for (int j = 0; j < NJ; ++j)
      acc[i][j] = (f32x4){0.f, 0.f, 0.f, 0.f};

  int frow = lane & 15;
  int fq = lane >> 4;
  int aoffs[NI], boffs[NJ];
#pragma unroll
  for (int i = 0; i < NI; ++i) {
    int ra = wrow + 16 * i + frow;
    aoffs[i] = ra * 32 + ((fq ^ (ra & 3)) << 3);
  }
#pragma unroll
  for (int j = 0; j < NJ; ++j) {
    int rb = wcol + 16 * j + frow;
    boffs[j] = rb * 32 + ((fq ^ (rb & 3)) << 3);
  }

  const short* Ah = Ab + (long long)(bm + arA + sr) * ldA + qg * 8;
  const short* Al = Ah + loA;
  const short* Bh = Bb + (long long)(bn + arB + sr) * ldB + qg * 8;
  const short* Bl = Bh + loB;
  int three = (nseg == 3);
  int btwo = (nseg >= 2);

  for (int ko = 0; ko < K; ko += 32) {
#pragma unroll
    for (int cc = 0; cc < NI / 2; ++cc) {
      gld16(Ah + ko + cc * 16 * ldA, &sAh[(arA + cc * 16) * 32]);
      if (three)
        gld16(Al + ko + cc * 16 * ldA, &sAl[(arA + cc * 16) * 32]);
    }
#pragma unroll
    for (int cc = 0; cc < NJ / 2; ++cc) {
      gld16(Bh + ko + cc * 16 * ldB, &sBh[(arB + cc * 16) * 32]);
      if (btwo)
        gld16(Bl + ko + cc * 16 * ldB, &sBl[(arB + cc * 16) * 32]);
    }
    __syncthreads();
    bf16x8 ah[NI], al[NI], bh[NJ], bl[NJ];
#pragma unroll
    for (int i = 0; i < NI; ++i) ah[i] = *(const bf16x8*)&sAh[aoffs[i]];
#pragma unroll
    for (int j = 0; j < NJ; ++j) bh[j] = *(const bf16x8*)&sBh[boffs[j]];
    if (btwo) {
#pragma unroll
      for (int j = 0; j < NJ; ++j) bl[j] = *(const bf16x8*)&sBl[boffs[j]];
    }
    if (three) {
#pragma unroll
      for (int i = 0; i < NI; ++i) al[i] = *(const bf16x8*)&sAl[aoffs[i]];
    }
#pragma unroll
    for (int i = 0; i < NI; ++i)
#pragma unroll
      for (int j = 0; j < NJ; ++j) {
        acc[i][j] = __builtin_amdgcn_mfma_f32_16x16x32_bf16(ah[i], bh[j], acc[i][j], 0, 0, 0);
        if (btwo)
          acc[i][j] = __builtin_amdgcn_mfma_f32_16x16x32_bf16(ah[i], bl[j], acc[i][j], 0, 0, 0);
        if (three)
          acc[i][j] = __builtin_amdgcn_mfma_f32_16x16x32_bf16(al[i], bh[j], acc[i][j], 0, 0, 0);
      }
    __syncthreads();
  }

  short* c2z = C2 ? (short*)C2 + (long long)z1 * bC21 + (long long)z2 * bC22 : nullptr;

  if (mode == 1) {
    // m = l (0..511), n = b*32+c -> XIH row = b*8 + l/64, col = (l%64)*32 + c
#pragma unroll
    for (int j = 0; j < NJ; ++j) {
      int n = bn + wcol + 16 * j + frow;
      int bidx = n >> 5, c = n & 31;
#pragma unroll
      for (int i = 0; i < NI; ++i)
#pragma unroll
        for (int r = 0; r < 4; ++r) {
          int m = bm + wrow + 16 * i + fq * 4 + r;
          int row = bidx * 8 + (m >> 6);
          int col = (m & 63) * 32 + c;
          ((__hip_bfloat16*)c2z)[(long long)row * 2048 + col] =
              __float2bfloat16(acc[i][j][r]);
        }
    }
    return;
  }

  const float* biasz = bias ? bias + (long long)z1 * bBias1 + (long long)z2 * bBias2 : nullptr;
  const float* addz  = Add  ? Add  + (long long)z1 * bAdd1  + (long long)z2 * bAdd2  : nullptr;
  float* cfz = Cf ? Cf + (long long)z1 * bCf1 + (long long)z2 * bCf2 : nullptr;

#pragma unroll
  for (int j = 0; j < NJ; ++j) {
    int n = bn + wcol + 16 * j + frow;
    float bv = biasz ? biasz[n] : 0.f;
#pragma unroll
    for (int i = 0; i < NI; ++i) {
#pragma unroll
      for (int r = 0; r < 4; ++r) {
        int m = bm + wrow + 16 * i + fq * 4 + r;
        float v = acc[i][j][r] + bv;
        if (addz) v += addz[(long long)m * ldadd + n];
        if (relu) v = fmaxf(v, 0.f);
        if (cfz) cfz[(long long)m * ldcf + n] = v;
        if (c2z) {
          __hip_bfloat16 h = __float2bfloat16(v);
          if (mode == 2) {
            __hip_bfloat16 l = __float2bfloat16(v - __bfloat162float(h));
            long long off = (long long)(m >> 3) * 8192 + (m & 7) * 512 + n;
            ((__hip_bfloat16*)c2z)[off] = h;
            ((__hip_bfloat16*)c2z)[off + 4096] = l;
          } else {
            ((__hip_bfloat16*)c2z)[(long long)m * ldc2 + n] = h;
            if (loC2) {
              __hip_bfloat16 l = __float2bfloat16(v - __bfloat162float(h));
              ((__hip_bfloat16*)c2z)[(long long)m * ldc2 + loC2 + n] = l;
            }
          }
        }
      }
    }
  }
}

// ---------------- LayerNorm over 512, writes bf16 hi-only [row, 512] ----------------
__global__ __launch_bounds__(256) void ln_kernel(
    const float* __restrict__ p, const float* __restrict__ g,
    const float* __restrict__ bb, __hip_bfloat16* __restrict__ p2)
{
  int row = blockIdx.x;              // NB*B*4 = 4096
  int nb = row >> 10;
  const float* pr = p + (size_t)row * 512;
  int tid = threadIdx.x;
  float v0 = pr[tid], v1 = pr[tid + 256];
  float s = v0 + v1, s2 = v0 * v0 + v1 * v1;
#pragma unroll
  for (int o = 32; o > 0; o >>= 1) {
    s += __shfl_down(s, o);
    s2 += __shfl_down(s2, o);
  }
  __shared__ float rs[4];
  __shared__ float rs2[4];
  int w = tid >> 6;
  if ((tid & 63) == 0) { rs[w] = s; rs2[w] = s2; }
  __syncthreads();
  s = rs[0] + rs[1] + rs[2] + rs[3];
  s2 = rs2[0] + rs2[1] + rs2[2] + rs2[3];
  float mval = s * (1.f / 512.f);
  float var = s2 * (1.f / 512.f) - mval * mval;
  float r = 1.f / sqrtf(var + EPSF);
  const float* gn = g + nb * 512;
  const float* bn = bb + nb * 512;
  float y0 = (v0 - mval) * r * gn[tid] + bn[tid];
  float y1 = (v1 - mval) * r * gn[tid + 256] + bn[tid + 256];
  __hip_bfloat16* o2 = p2 + (size_t)nb * 524288 + (size_t)(row & 1023) * 512;
  o2[tid] = __float2bfloat16(y0);
  o2[tid + 256] = __float2bfloat16(y1);
}

// ---------------- final: out = (sum_nb deco) * std + mean ----------------
__global__ __launch_bounds__(256) void final_kernel(
    const float* __restrict__ deco, const float* __restrict__ meanp,
    const float* __restrict__ stdp, float* __restrict__ out)
{
  int t = blockIdx.x * 256 + threadIdx.x;
  int b = t >> 11;
  int r = t & 2047;
  int p = (r >> 3) & 63;
  int cq = r & 7;
  size_t base = ((size_t)(b * 4 + (r >> 9))) * 2048 + p * 32 + cq * 4;
  const size_t nbs = 1024ull * 2048ull;
  float4 a0 = *(const float4*)(deco + base);
  float4 a1 = *(const float4*)(deco + nbs + base);
  float4 a2 = *(const float4*)(deco + 2 * nbs + base);
  float4 a3 = *(const float4*)(deco + 3 * nbs + base);
  float4 m4 = *(const float4*)(meanp + b * 32 + cq * 4);
  float4 s4 = *(const float4*)(stdp + b * 32 + cq * 4);
  float4 o;
  o.x = (a0.x + a1.x + a2.x + a3.x) * s4.x + m4.x;
  o.y = (a0.y + a1.y + a2.y + a3.y) * s4.y + m4.y;
  o.z = (a0.z + a1.z + a2.z + a3.z) * s4.z + m4.z;
  o.w = (a0.w + a1.w + a2.w + a3.w) * s4.w + m4.w;
  *(float4*)(out + (size_t)t * 4) = o;
}

extern "C" void kernel_launch(void* const* d_in, const int* in_sizes, int n_in,
                              void* d_out, int out_size, void* d_ws, size_t ws_size,
                              hipStream_t stream) {
  const float* x_enc  = (const float*)d_in[0];
  const float* mask_w = (const float*)d_in[4];
  const float* enc_w1 = (const float*)d_in[5];
  const float* enc_b1 = (const float*)d_in[6];
  const float* enc_w2 = (const float*)d_in[7];
  const float* enc_b2 = (const float*)d_in[8];
  const float* wxh    = (const float*)d_in[9];
  const float* whh    = (const float*)d_in[10];
  const float* ln_g   = (const float*)d_in[11];
  const float* ln_b   = (const float*)d_in[12];
  const float* dec_w1 = (const float*)d_in[13];
  const float* dec_b1 = (const float*)d_in[14];
  const float* dec_w2 = (const float*)d_in[15];
  const float* dec_b2 = (const float*)d_in[16];
  float* out = (float*)d_out;

  typedef __hip_bfloat16 bf;
  char* W = (char*)d_ws;
  float* MEAN = (float*)(W);
  float* STD  = (float*)(W + 32768);
  float* RSTD = (float*)(W + 65536);
  float* KF   = (float*)(W + 98304);
  char* B0 = W + 131072;
  // ---- corrected sizes (MB offsets from B0); peak 112 MB ----
  // phase 1:
  bf* XIH   = (bf*)(B0);                    // [0,32)    dead after enc1
  bf* XNB   = (bf*)(B0 + 33554432);         // [32,48)   dead after conv
  bf* CM    = (bf*)(B0 + 50331648);         // [48,52)   dead after conv
  bf* WW    = (bf*)(B0 + 33554432);         // [32,48)   16MB hi, written post-conv, dead after enc1
  bf* ENCB2 = (bf*)(B0 + 67108864);         // [64,80)   16MB hi, dead after enc2
  // weight splits (launched after enc1; [0,64) free except nothing):
  bf* EW2   = (bf*)(B0);                    // [0,4)     4MB hi, dead after enc2
  bf* WXH2  = (bf*)(B0 + 4194304);          // [4,6)     2MB hi, dead after xp
  bf* DW1   = (bf*)(B0 + 6291456);          // [6,10)    4MB hi, read at dec1
  bf* DW2   = (bf*)(B0 + 10485760);         // [10,26)   16MB hi, read at dec2
  bf* WSP   = (bf*)(B0 + 27262976);         // [26,30)   4MB hi|lo, dead after free-run A
  bf* W2SP  = (bf*)(B0 + 31457280);         // [30,34)   4MB hi|lo, dead after free-run B
  bf* WTSP  = (bf*)(B0 + 35651584);         // [34,38)   4MB hi|lo, dead after W2 GEMM
  bf* ENC22 = (bf*)(B0 + 39845888);         // [38,46)   8MB hi, dead after xp
  float* XP = (float*)(B0 + 48234496);      // [46,62)   16MB fp32, dead after y-combine
  bf* XP2   = (bf*)(B0 + 67108864);         // [64,80)   16MB hi|lo (ENCB2 dead), dead after y-combine
  float* YF = (float*)(B0 + 83886080);      // [80,88)   8MB, dead after Horner-3
  bf* Y2    = (bf*)(B0 + 92274688);         // [88,96)   8MB hi|lo, dead after Horner-1
  bf* H2    = (bf*)(B0 + 100663296);        // [96,98)
  bf* H22   = (bf*)(B0 + 102760448);        // [98,100)
  bf* P12   = (bf*)(B0 + 104857600);        // [100,104)
  float* PREDS = (float*)(B0 + 109051904);  // [104,112)
  bf* PREDS2 = (bf*)(B0);                   // [0,4)     4MB hi, written at ln (EW2 dead)
  bf* DBUF2 = (bf*)(B0 + 83886080);         // [80,88)   8MB hi, dec1 out (YF dead)
  float* DECO = (float*)(B0 + 33554432);    // [32,64)   32MB, dec2 out (WTSP/ENC22/XP/W2SP-tail all dead)

  stats_kernel<<<256, 256, 0, stream>>>(x_enc, MEAN, STD, RSTD);
  kfilt_kernel<<<8, 256, 0, stream>>>(mask_w, KF);
  xprep_kernel<<<256, 256, 0, stream>>>(x_enc, MEAN, RSTD, XNB);
  cmat_kernel<<<512, 256, 0, stream>>>(KF, CM);

  // conv as MFMA GEMM (A=CM hi, nseg=2): per nb [512,512] @ [8192,512]^T -> XIH scatter
  gemm_mfma<4, 4><<<dim3(64, 4, 4), 256, 0, stream>>>(
      CM, 1024, 524288LL, 0LL, 0, XNB, 1024, 0LL, 0LL, 512,
      nullptr, 0, 0, nullptr, 0, 0, 0, nullptr, 0, 0, 0,
      XIH, 0, 0, 4194304LL, 0LL, 1, 512, 8192, 512, 2, 0, 1, 0);

  // enc1: M=2048 N=1024 K=2048, pure bf16 (nseg=1), relu, hi out; swapg A-local
  splith_kernel<<<8192, 256, 0, stream>>>(enc_w1, WW);
  gemm_mfma<4, 2><<<dim3(16, 16, 4), 256, 0, stream>>>(
      XIH, 2048, 4194304LL, 0LL, 0, WW, 2048, 2097152LL, 0LL, 0,
      enc_b1, 1024LL, 0LL, nullptr, 0, 0, 0, nullptr, 0, 0, 0,
      ENCB2, 1024, 0, 2097152LL, 0LL, 1, 2048, 1024, 2048, 1, 1, 0, 1);

  splith_kernel<<<2048, 256, 0, stream>>>(enc_w2, EW2);
  splith_kernel<<<1024, 256, 0, stream>>>(wxh, WXH2);
  splith_kernel<<<2048, 256, 0, stream>>>(dec_w1, DW1);
  splith_kernel<<<8192, 256, 0, stream>>>(dec_w2, DW2);
  split_kernel<<<1024, 256, 0, stream>>>(whh, WSP, 9);
  tsplit_kernel<<<dim3(8, 8, 4), 256, 0, stream>>>(whh, WTSP);

  // enc2: M=2048 N=512 K=1024, nseg=1, hi out; swapg
  gemm_mfma<4, 2><<<dim3(16, 8, 4), 256, 0, stream>>>(
      ENCB2, 1024, 2097152LL, 0LL, 0, EW2, 1024, 524288LL, 0LL, 0,
      enc_b2, 512LL, 0LL, nullptr, 0, 0, 0, nullptr, 0, 0, 0,
      ENC22, 512, 0, 1048576LL, 0LL, 1, 2048, 512, 1024, 1, 0, 0, 1);

  // xp = enc2 @ wxh^T: nseg=1; fp32 out + XP2 hi|lo-concat (mode 2); swapg
  gemm_mfma<4, 2><<<dim3(16, 8, 4), 256, 0, stream>>>(
      ENC22, 512, 1048576LL, 0LL, 0, WXH2, 512, 262144LL, 0LL, 0,
      nullptr, 0, 0, nullptr, 0, 0, 0, XP, 512, 1048576LL, 0LL,
      XP2, 0, 0, 2097152LL, 0LL, 1, 2048, 512, 512, 1, 0, 2, 1);

  // W2 = W @ W (nseg=3) -> split-out W2SP
  gemm_mfma<2, 2><<<dim3(8, 8, 4), 256, 0, stream>>>(
      WSP, 1024, 524288LL, 0LL, 512, WTSP, 1024, 524288LL, 0LL, 512,
      nullptr, 0, 0, nullptr, 0, 0, 0, nullptr, 0, 0, 0,
      W2SP, 1024, 512, 524288LL, 0LL, 1, 512, 512, 512, 3, 0, 0, 0);

  // y_j = xp_{2j} @ W^T + xp_{2j+1}   (z1 = j, z2 = nb, 16 total), nseg=3
  gemm_mfma<2, 2><<<dim3(8, 4, 16), 256, 0, stream>>>(
      XP2, 8192, 1024LL, 2097152LL, 4096, WSP, 1024, 0LL, 524288LL, 512,
      nullptr, 0, 0, XP + 512, 4096, 1024LL, 1048576LL,
      YF, 512, 524288LL, 131072LL,
      Y2, 1024, 512, 1048576LL, 262144LL, 4, 256, 512, 512, 3, 0, 0, 0);

  // Horner with W2 (nseg=3)
  gemm_mfma<2, 2><<<dim3(8, 4, 4), 256, 0, stream>>>(
      Y2, 1024, 0LL, 262144LL, 512, W2SP, 1024, 0LL, 524288LL, 512,
      nullptr, 0, 0, YF + 524288, 512, 0LL, 131072LL, nullptr, 0, 0, 0,
      H2, 1024, 512, 0LL, 262144LL, 4, 256, 512, 512, 3, 0, 0, 0);
  gemm_mfma<2, 2><<<dim3(8, 4, 4), 256, 0, stream>>>(
      H2, 1024, 0LL, 262144LL, 512, W2SP, 1024, 0LL, 524288LL, 512,
      nullptr, 0, 0, YF + 1048576, 512, 0LL, 131072LL, nullptr, 0, 0, 0,
      H22, 1024, 512, 0LL, 262144LL, 4, 256, 512, 512, 3, 0, 0, 0);
  gemm_mfma<2, 2><<<dim3(8, 4, 4), 256, 0, stream>>>(
      H22, 1024, 0LL, 262144LL, 512, W2SP, 1024, 0LL, 524288LL, 512,
      nullptr, 0, 0, YF + 1572864, 512, 0LL, 131072LL, nullptr, 0, 0, 0,
      H2, 1024, 512, 0LL, 262144LL, 4, 256, 512, 512, 3, 0, 0, 0);

  // free-run A: p1 = h@W^T (z1=0), p2 = h@W2^T (z1=1), nseg=3
  gemm_mfma<2, 2><<<dim3(8, 4, 8), 256, 0, stream>>>(
      H2, 1024, 0LL, 262144LL, 512, WSP, 1024, 2097152LL, 524288LL, 512,
      nullptr, 0, 0, nullptr, 0, 0, 0, PREDS, 2048, 512LL, 524288LL,
      P12, 1024, 512, 1048576LL, 262144LL, 4, 256, 512, 512, 3, 0, 0, 0);
  // free-run B: p3 = p1@W2^T, p4 = p2@W2^T, nseg=3
  gemm_mfma<2, 2><<<dim3(8, 4, 8), 256, 0, stream>>>(
      P12, 1024, 1048576LL, 262144LL, 512, W2SP, 1024, 0LL, 524288LL, 512,
      nullptr, 0, 0, nullptr, 0, 0, 0, PREDS + 1024, 2048, 512LL, 524288LL,
      nullptr, 0, 0, 0LL, 0LL, 4, 256, 512, 512, 3, 0, 0, 0);

  ln_kernel<<<4096, 256, 0, stream>>>(PREDS, ln_g, ln_b, PREDS2);

  // dec1: M=1024 N=1024 K=512, nseg=1, relu, hi out
  gemm_mfma<4, 2><<<dim3(16, 8, 4), 256, 0, stream>>>(
      PREDS2, 512, 524288LL, 0LL, 0, DW1, 512, 524288LL, 0LL, 0,
      dec_b1, 1024LL, 0LL, nullptr, 0, 0, 0, nullptr, 0, 0, 0,
      DBUF2, 1024, 0, 1048576LL, 0LL, 1, 1024, 1024, 512, 1, 1, 0, 0);
  // dec2: M=1024 N=2048 K=1024, nseg=1, fp32 out
  gemm_mfma<4, 2><<<dim3(32, 8, 4), 256, 0, stream>>>(
      DBUF2, 1024, 1048576LL, 0LL, 0, DW2, 1024, 2097152LL, 0LL, 0,
      dec_b2, 2048LL, 0LL, nullptr, 0, 0, 0, DECO, 2048, 2097152LL, 0LL,
      nullptr, 0, 0, 0LL, 0LL, 1, 1024, 2048, 1024, 1, 0, 0, 0);

  final_kernel<<<2048, 256, 0, stream>>>(DECO, MEAN, STD, out);
}

// Round 10
// 556.789 us; speedup vs baseline: 1.9580x; 1.0992x over previous
//
#include <hip/hip_runtime.h>
#include <hip/hip_bf16.h>
#include <math.h>

#define EPSF 1e-5f

typedef __attribute__((ext_vector_type(8))) short bf16x8;
typedef __attribute__((ext_vector_type(4))) float f32x4;

__device__ __forceinline__ void gld16(const void* g, void* l) {
  __builtin_amdgcn_global_load_lds(
      (const __attribute__((address_space(1))) unsigned int*)g,
      (__attribute__((address_space(3))) unsigned int*)l, 16, 0, 0);
}

// ---------------- fused instance-norm stats + normalize + transpose + hi/lo split ----------------
// x[b]: [512,32] -> XNB[b*32+c][l' hi | l'+512 lo]; also writes mean/std [B,32]
__global__ __launch_bounds__(256) void prep_kernel(
    const float* __restrict__ x, float* __restrict__ meanp,
    float* __restrict__ stdp, __hip_bfloat16* __restrict__ xnb)
{
  __shared__ float xs[512 * 33];
  __shared__ float red[8][32];
  __shared__ float red2[8][32];
  __shared__ float sm[32];
  __shared__ float srr[32];
  int b = blockIdx.x, tid = threadIdx.x;
  const float* xb = x + (size_t)b * 16384;
#pragma unroll
  for (int i = 0; i < 16; ++i) {
    int idx4 = tid + i * 256;
    int l = idx4 >> 3, c0 = (idx4 & 7) * 4;
    float4 v = *(const float4*)(xb + idx4 * 4);
    xs[l * 33 + c0 + 0] = v.x;
    xs[l * 33 + c0 + 1] = v.y;
    xs[l * 33 + c0 + 2] = v.z;
    xs[l * 33 + c0 + 3] = v.w;
  }
  __syncthreads();
  int c = tid & 31, ls = tid >> 5;
  float s = 0.f, s2 = 0.f;
  for (int l = ls; l < 512; l += 8) {
    float v = xs[l * 33 + c];
    s += v; s2 += v * v;
  }
  red[ls][c] = s; red2[ls][c] = s2;
  __syncthreads();
  if (ls == 0) {
#pragma unroll
    for (int i = 1; i < 8; ++i) { s += red[i][c]; s2 += red2[i][c]; }
    float m = s * (1.f / 512.f);
    float var = s2 * (1.f / 512.f) - m * m;
    float sd = sqrtf(var + EPSF);
    meanp[b * 32 + c] = m;
    stdp[b * 32 + c] = sd;
    sm[c] = m;
    srr[c] = 1.f / sd;
  }
  __syncthreads();
  for (int cc = 0; cc < 32; ++cc) {
    float m = sm[cc];
    float r = srr[cc];
    int l = tid * 2;
    float v0 = (xs[l * 33 + cc] - m) * r;
    float v1 = (xs[(l + 1) * 33 + cc] - m) * r;
    __hip_bfloat16 h0 = __float2bfloat16(v0);
    __hip_bfloat16 h1 = __float2bfloat16(v1);
    union { __hip_bfloat16 h[2]; unsigned int u; } H, L;
    H.h[0] = h0; H.h[1] = h1;
    L.h[0] = __float2bfloat16(v0 - __bfloat162float(h0));
    L.h[1] = __float2bfloat16(v1 - __bfloat162float(h1));
    unsigned int* dst =
        (unsigned int*)((unsigned short*)xnb + ((size_t)(b * 32 + cc)) * 1024 + l);
    dst[0] = H.u;
    dst[256] = L.u;
  }
}

// ---------------- Fourier-mask -> time-domain filter taps (duplicated) ----------------
__global__ __launch_bounds__(256) void kfilt_kernel(
    const float* __restrict__ mw, float* __restrict__ kf)
{
  int gid = blockIdx.x * 256 + threadIdx.x;
  int nb = gid >> 9, t = gid & 511;
  const float* m = mw + nb * 257;
  float s0 = 1.f / (1.f + expf(-m[0]));
  float sN = 1.f / (1.f + expf(-m[256]));
  float acc = s0 + ((t & 1) ? -sN : sN);
  for (int f = 1; f < 256; ++f) {
    float sig = 1.f / (1.f + expf(-m[f]));
    int tf = (t * f) & 511;
    acc += 2.f * sig * cosf(6.28318530717958647f * (float)tf * (1.f / 512.f));
  }
  float kv = acc * (1.f / 512.f);
  kf[nb * 1024 + t] = kv;
  kf[nb * 1024 + t + 512] = kv;
}

// ---------------- circulant matrix build: CM[nb][l][l' | l'+512] bf16 hi|lo ----------------
__global__ __launch_bounds__(256) void cmat_kernel(
    const float* __restrict__ kf, __hip_bfloat16* __restrict__ cm)
{
  int t = threadIdx.x;
  int row = blockIdx.x * 4 + (t >> 6);
  int nb = row >> 9, l = row & 511;
  int lp0 = (t & 63) * 8;
  union { __hip_bfloat16 h[8]; uint4 u; } H, L;
#pragma unroll
  for (int j = 0; j < 8; ++j) {
    float v = kf[nb * 1024 + 512 + l - (lp0 + j)];
    __hip_bfloat16 h = __float2bfloat16(v);
    H.h[j] = h;
    L.h[j] = __float2bfloat16(v - __bfloat162float(h));
  }
  unsigned short* dst = (unsigned short*)cm + (size_t)row * 1024 + lp0;
  *(uint4*)dst = H.u;
  *(uint4*)(dst + 512) = L.u;
}

// ---------------- fp32 -> bf16 hi/lo split: in [rows,K] -> out [rows,2K] ----------------
__global__ __launch_bounds__(256) void split_kernel(
    const float* __restrict__ in, __hip_bfloat16* __restrict__ out, int ks)
{
  int t = blockIdx.x * 256 + threadIdx.x;
  long long idx = (long long)t * 4;
  int K = 1 << ks;
  long long r = idx >> ks;
  int k = (int)(idx & (K - 1));
  float4 v = *(const float4*)(in + idx);
  float vv[4] = {v.x, v.y, v.z, v.w};
  union { __hip_bfloat16 h[4]; uint2 u; } H, L;
#pragma unroll
  for (int u = 0; u < 4; ++u) {
    H.h[u] = __float2bfloat16(vv[u]);
    L.h[u] = __float2bfloat16(vv[u] - __bfloat162float(H.h[u]));
  }
  unsigned short* ob = (unsigned short*)out + (r << (ks + 1)) + k;
  *(uint2*)ob = H.u;
  *(uint2*)(ob + K) = L.u;
}

// ---------------- fp32 -> bf16 hi-only cast (dense, single source) ----------------
__global__ __launch_bounds__(256) void splith_kernel(
    const float* __restrict__ in, __hip_bfloat16* __restrict__ out)
{
  long long idx = ((long long)blockIdx.x * 256 + threadIdx.x) * 4;
  float4 v = *(const float4*)(in + idx);
  union { __hip_bfloat16 h[4]; uint2 u; } H;
  H.h[0] = __float2bfloat16(v.x);
  H.h[1] = __float2bfloat16(v.y);
  H.h[2] = __float2bfloat16(v.z);
  H.h[3] = __float2bfloat16(v.w);
  *(uint2*)((unsigned short*)out + idx) = H.u;
}

// ---------------- fused hi-only cast of 4 weights into contiguous dest ----------------
// ranges (float4 units): enc_w2 524288 | wxh 262144 | dec_w1 524288 | dec_w2 2097152
__global__ __launch_bounds__(256) void splith4_kernel(
    const float* __restrict__ s0, const float* __restrict__ s1,
    const float* __restrict__ s2, const float* __restrict__ s3,
    __hip_bfloat16* __restrict__ out)
{
  long long i4 = (long long)blockIdx.x * 256 + threadIdx.x;  // 3,407,872 total
  const float* src;
  long long lo;
  if (i4 < 524288)        { src = s0; lo = i4; }
  else if (i4 < 786432)   { src = s1; lo = i4 - 524288; }
  else if (i4 < 1310720)  { src = s2; lo = i4 - 786432; }
  else                    { src = s3; lo = i4 - 1310720; }
  float4 v = ((const float4*)src)[lo];
  union { __hip_bfloat16 h[4]; uint2 u; } H;
  H.h[0] = __float2bfloat16(v.x);
  H.h[1] = __float2bfloat16(v.y);
  H.h[2] = __float2bfloat16(v.z);
  H.h[3] = __float2bfloat16(v.w);
  *(uint2*)((unsigned short*)out + i4 * 4) = H.u;
}

// ---------------- transpose + split: WT2[nb][col][hi 512 | lo 512] = whh^T ----------------
__global__ __launch_bounds__(256) void tsplit_kernel(
    const float* __restrict__ w, __hip_bfloat16* __restrict__ wt2)
{
  __shared__ float ts[64][65];
  int bx = blockIdx.x, by = blockIdx.y, nb = blockIdx.z;
  int t = threadIdx.x;
  int tr = t >> 4, c0 = (t & 15) * 4;
  const float* wb = w + (size_t)nb * 262144;
#pragma unroll
  for (int k = 0; k < 4; ++k) {
    int r = tr + k * 16;
    float4 v = *(const float4*)(wb + (size_t)(by * 64 + r) * 512 + bx * 64 + c0);
    ts[r][c0 + 0] = v.x; ts[r][c0 + 1] = v.y;
    ts[r][c0 + 2] = v.z; ts[r][c0 + 3] = v.w;
  }
  __syncthreads();
  unsigned short* ob = (unsigned short*)wt2 + (size_t)nb * 524288;
#pragma unroll
  for (int k = 0; k < 4; ++k) {
    int r = tr + k * 16;
    float vv[4] = {ts[c0][r], ts[c0 + 1][r], ts[c0 + 2][r], ts[c0 + 3][r]};
    union { __hip_bfloat16 h[4]; uint2 u; } H, L;
#pragma unroll
    for (int j = 0; j < 4; ++j) {
      H.h[j] = __float2bfloat16(vv[j]);
      L.h[j] = __float2bfloat16(vv[j] - __bfloat162float(H.h[j]));
    }
    size_t row = (size_t)(bx * 64 + r);
    *(uint2*)(ob + row * 1024 + by * 64 + c0) = H.u;
    *(uint2*)(ob + row * 1024 + 512 + by * 64 + c0) = L.u;
  }
}

// ---------------- split-bf16 MFMA GEMM, compile-time NSEG, tiled by template ----------------
// Tile = (32*NI) x (32*NJ), 256 thr (4 waves, 2x2). BK=32, 16x16x32 bf16 MFMA.
// NSEG1: Ahi*Bhi   NSEG2: Ahi*(Bhi+Blo)   NSEG3: + Alo*Bhi
// swapg=1: blockIdx.x indexes M-tiles (XCD-local A stripes)
// z-batching two-level: off = (bz/nz2)*b?1 + (bz%nz2)*b?2 (element units).
// mode 0: normal epilogue (bias, Add fp32, relu, Cf fp32, C2 hi at ldc2 [+lo at loC2 if !=0])
// mode 1: XIH scatter (conv output, hi only)
// mode 2: Cf normal + C2 as XP concat [b][f*512+n | 4096+f*512+n]
template<int NI, int NJ, int NSEG>
__global__ __launch_bounds__(256) void gemm_mfma(
    const __hip_bfloat16* __restrict__ A_, int ldA, long long bA1, long long bA2, int loA,
    const __hip_bfloat16* __restrict__ B_, int ldB, long long bB1, long long bB2, int loB,
    const float* __restrict__ bias, long long bBias1, long long bBias2,
    const float* __restrict__ Add, int ldadd, long long bAdd1, long long bAdd2,
    float* __restrict__ Cf, int ldcf, long long bCf1, long long bCf2,
    __hip_bfloat16* __restrict__ C2, int ldc2, int loC2, long long bC21, long long bC22,
    int nz2, int M, int N, int K, int relu, int mode, int swapg)
{
  constexpr bool three = (NSEG == 3);
  constexpr bool btwo = (NSEG >= 2);
  __shared__ short sAh[32 * NI * 32];
  __shared__ short sAl[three ? 32 * NI * 32 : 1];
  __shared__ short sBh[32 * NJ * 32];
  __shared__ short sBl[btwo ? 32 * NJ * 32 : 1];
  int z1 = blockIdx.z / nz2, z2 = blockIdx.z % nz2;
  const short* Ab = (const short*)A_ + (long long)z1 * bA1 + (long long)z2 * bA2;
  const short* Bb = (const short*)B_ + (long long)z1 * bB1 + (long long)z2 * bB2;
  int tid = threadIdx.x, wave = tid >> 6, lane = tid & 63;
  int bxv = swapg ? blockIdx.y : blockIdx.x;
  int byv = swapg ? blockIdx.x : blockIdx.y;
  int bm = byv * (32 * NI), bn = bxv * (32 * NJ);
  int wrow = (wave >> 1) * (16 * NI), wcol = (wave & 1) * (16 * NJ);

  int sr = lane >> 2;
  int qg = (lane & 3) ^ (sr & 3);
  int arA = wave * 8 * NI;
  int arB = wave * 8 * NJ;

  f32x4 acc[NI][NJ];
#pragma unroll
  for (int i = 0; i < NI; ++i)
#pragma unroll
    for (int j = 0; j < NJ; ++j)
      acc[i][j] = (f32x4){0.f, 0.f, 0.f, 0.f};

  int frow = lane & 15;
  int fq = lane >> 4;
  int aoffs[NI], boffs[NJ];
#pragma unroll
  for (int i = 0; i < NI; ++i) {
    int ra = wrow + 16 * i + frow;
    aoffs[i] = ra * 32 + ((fq ^ (ra & 3)) << 3);
  }
#pragma unroll
  for (int j = 0; j < NJ; ++j) {
    int rb = wcol + 16 * j + frow;
    boffs[j] = rb * 32 + ((fq ^ (rb & 3)) << 3);
  }

  const short* Ah = Ab + (long long)(bm + arA + sr) * ldA + qg * 8;
  const short* Al = Ah + loA;
  const short* Bh = Bb + (long long)(bn + arB + sr) * ldB + qg * 8;
  const short* Bl = Bh + loB;

  for (int ko = 0; ko < K; ko += 32) {
#pragma unroll
    for (int cc = 0; cc < NI / 2; ++cc) {
      gld16(Ah + ko + cc * 16 * ldA, &sAh[(arA + cc * 16) * 32]);
      if constexpr (three)
        gld16(Al + ko + cc * 16 * ldA, &sAl[(arA + cc * 16) * 32]);
    }
#pragma unroll
    for (int cc = 0; cc < NJ / 2; ++cc) {
      gld16(Bh + ko + cc * 16 * ldB, &sBh[(arB + cc * 16) * 32]);
      if constexpr (btwo)
        gld16(Bl + ko + cc * 16 * ldB, &sBl[(arB + cc * 16) * 32]);
    }
    __syncthreads();
    bf16x8 ah[NI], al[NI], bh[NJ], bl[NJ];
#pragma unroll
    for (int i = 0; i < NI; ++i) ah[i] = *(const bf16x8*)&sAh[aoffs[i]];
#pragma unroll
    for (int j = 0; j < NJ; ++j) bh[j] = *(const bf16x8*)&sBh[boffs[j]];
    if constexpr (btwo) {
#pragma unroll
      for (int j = 0; j < NJ; ++j) bl[j] = *(const bf16x8*)&sBl[boffs[j]];
    }
    if constexpr (three) {
#pragma unroll
      for (int i = 0; i < NI; ++i) al[i] = *(const bf16x8*)&sAl[aoffs[i]];
    }
#pragma unroll
    for (int i = 0; i < NI; ++i)
#pragma unroll
      for (int j = 0; j < NJ; ++j) {
        acc[i][j] = __builtin_amdgcn_mfma_f32_16x16x32_bf16(ah[i], bh[j], acc[i][j], 0, 0, 0);
        if constexpr (btwo)
          acc[i][j] = __builtin_amdgcn_mfma_f32_16x16x32_bf16(ah[i], bl[j], acc[i][j], 0, 0, 0);
        if constexpr (three)
          acc[i][j] = __builtin_amdgcn_mfma_f32_16x16x32_bf16(al[i], bh[j], acc[i][j], 0, 0, 0);
      }
    __syncthreads();
  }

  short* c2z = C2 ? (short*)C2 + (long long)z1 * bC21 + (long long)z2 * bC22 : nullptr;

  if (mode == 1) {
    // m = l (0..511), n = b*32+c -> XIH row = b*8 + l/64, col = (l%64)*32 + c
#pragma unroll
    for (int j = 0; j < NJ; ++j) {
      int n = bn + wcol + 16 * j + frow;
      int bidx = n >> 5, c = n & 31;
#pragma unroll
      for (int i = 0; i < NI; ++i)
#pragma unroll
        for (int r = 0; r < 4; ++r) {
          int m = bm + wrow + 16 * i + fq * 4 + r;
          int row = bidx * 8 + (m >> 6);
          int col = (m & 63) * 32 + c;
          ((__hip_bfloat16*)c2z)[(long long)row * 2048 + col] =
              __float2bfloat16(acc[i][j][r]);
        }
    }
    return;
  }

  const float* biasz = bias ? bias + (long long)z1 * bBias1 + (long long)z2 * bBias2 : nullptr;
  const float* addz  = Add  ? Add  + (long long)z1 * bAdd1  + (long long)z2 * bAdd2  : nullptr;
  float* cfz = Cf ? Cf + (long long)z1 * bCf1 + (long long)z2 * bCf2 : nullptr;

#pragma unroll
  for (int j = 0; j < NJ; ++j) {
    int n = bn + wcol + 16 * j + frow;
    float bv = biasz ? biasz[n] : 0.f;
#pragma unroll
    for (int i = 0; i < NI; ++i) {
#pragma unroll
      for (int r = 0; r < 4; ++r) {
        int m = bm + wrow + 16 * i + fq * 4 + r;
        float v = acc[i][j][r] + bv;
        if (addz) v += addz[(long long)m * ldadd + n];
        if (relu) v = fmaxf(v, 0.f);
        if (cfz) cfz[(long long)m * ldcf + n] = v;
        if (c2z) {
          __hip_bfloat16 h = __float2bfloat16(v);
          if (mode == 2) {
            __hip_bfloat16 l = __float2bfloat16(v - __bfloat162float(h));
            long long off = (long long)(m >> 3) * 8192 + (m & 7) * 512 + n;
            ((__hip_bfloat16*)c2z)[off] = h;
            ((__hip_bfloat16*)c2z)[off + 4096] = l;
          } else {
            ((__hip_bfloat16*)c2z)[(long long)m * ldc2 + n] = h;
            if (loC2) {
              __hip_bfloat16 l = __float2bfloat16(v - __bfloat162float(h));
              ((__hip_bfloat16*)c2z)[(long long)m * ldc2 + loC2 + n] = l;
            }
          }
        }
      }
    }
  }
}

// ---------------- LayerNorm over 512, writes bf16 hi-only [row, 512] ----------------
__global__ __launch_bounds__(256) void ln_kernel(
    const float* __restrict__ p, const float* __restrict__ g,
    const float* __restrict__ bb, __hip_bfloat16* __restrict__ p2)
{
  int row = blockIdx.x;              // NB*B*4 = 4096
  int nb = row >> 10;
  const float* pr = p + (size_t)row * 512;
  int tid = threadIdx.x;
  float v0 = pr[tid], v1 = pr[tid + 256];
  float s = v0 + v1, s2 = v0 * v0 + v1 * v1;
#pragma unroll
  for (int o = 32; o > 0; o >>= 1) {
    s += __shfl_down(s, o);
    s2 += __shfl_down(s2, o);
  }
  __shared__ float rs[4];
  __shared__ float rs2[4];
  int w = tid >> 6;
  if ((tid & 63) == 0) { rs[w] = s; rs2[w] = s2; }
  __syncthreads();
  s = rs[0] + rs[1] + rs[2] + rs[3];
  s2 = rs2[0] + rs2[1] + rs2[2] + rs2[3];
  float mval = s * (1.f / 512.f);
  float var = s2 * (1.f / 512.f) - mval * mval;
  float r = 1.f / sqrtf(var + EPSF);
  const float* gn = g + nb * 512;
  const float* bn = bb + nb * 512;
  float y0 = (v0 - mval) * r * gn[tid] + bn[tid];
  float y1 = (v1 - mval) * r * gn[tid + 256] + bn[tid + 256];
  __hip_bfloat16* o2 = p2 + (size_t)nb * 524288 + (size_t)(row & 1023) * 512;
  o2[tid] = __float2bfloat16(y0);
  o2[tid + 256] = __float2bfloat16(y1);
}

// ---------------- final: out = (sum_nb deco) * std + mean ----------------
__global__ __launch_bounds__(256) void final_kernel(
    const float* __restrict__ deco, const float* __restrict__ meanp,
    const float* __restrict__ stdp, float* __restrict__ out)
{
  int t = blockIdx.x * 256 + threadIdx.x;
  int b = t >> 11;
  int r = t & 2047;
  int p = (r >> 3) & 63;
  int cq = r & 7;
  size_t base = ((size_t)(b * 4 + (r >> 9))) * 2048 + p * 32 + cq * 4;
  const size_t nbs = 1024ull * 2048ull;
  float4 a0 = *(const float4*)(deco + base);
  float4 a1 = *(const float4*)(deco + nbs + base);
  float4 a2 = *(const float4*)(deco + 2 * nbs + base);
  float4 a3 = *(const float4*)(deco + 3 * nbs + base);
  float4 m4 = *(const float4*)(meanp + b * 32 + cq * 4);
  float4 s4 = *(const float4*)(stdp + b * 32 + cq * 4);
  float4 o;
  o.x = (a0.x + a1.x + a2.x + a3.x) * s4.x + m4.x;
  o.y = (a0.y + a1.y + a2.y + a3.y) * s4.y + m4.y;
  o.z = (a0.z + a1.z + a2.z + a3.z) * s4.z + m4.z;
  o.w = (a0.w + a1.w + a2.w + a3.w) * s4.w + m4.w;
  *(float4*)(out + (size_t)t * 4) = o;
}

extern "C" void kernel_launch(void* const* d_in, const int* in_sizes, int n_in,
                              void* d_out, int out_size, void* d_ws, size_t ws_size,
                              hipStream_t stream) {
  const float* x_enc  = (const float*)d_in[0];
  const float* mask_w = (const float*)d_in[4];
  const float* enc_w1 = (const float*)d_in[5];
  const float* enc_b1 = (const float*)d_in[6];
  const float* enc_w2 = (const float*)d_in[7];
  const float* enc_b2 = (const float*)d_in[8];
  const float* wxh    = (const float*)d_in[9];
  const float* whh    = (const float*)d_in[10];
  const float* ln_g   = (const float*)d_in[11];
  const float* ln_b   = (const float*)d_in[12];
  const float* dec_w1 = (const float*)d_in[13];
  const float* dec_b1 = (const float*)d_in[14];
  const float* dec_w2 = (const float*)d_in[15];
  const float* dec_b2 = (const float*)d_in[16];
  float* out = (float*)d_out;

  typedef __hip_bfloat16 bf;
  char* W = (char*)d_ws;
  float* MEAN = (float*)(W);
  float* STD  = (float*)(W + 32768);
  float* KF   = (float*)(W + 98304);
  char* B0 = W + 131072;
  // ---- layout (MB offsets from B0); peak 112 MB; lifetimes as R9 (verified) ----
  bf* XIH   = (bf*)(B0);                    // [0,32)    dead after enc1
  bf* XNB   = (bf*)(B0 + 33554432);         // [32,48)   dead after conv
  bf* CM    = (bf*)(B0 + 50331648);         // [48,52)   dead after conv
  bf* WW    = (bf*)(B0 + 33554432);         // [32,48)   16MB hi, written post-conv, dead after enc1
  bf* ENCB2 = (bf*)(B0 + 67108864);         // [64,80)   16MB hi, dead after enc2
  // weight splits (after enc1; splith4 dest = [0,26) contiguous):
  bf* EW2   = (bf*)(B0);                    // [0,4)     4MB hi
  bf* WXH2  = (bf*)(B0 + 4194304);          // [4,6)     2MB hi
  bf* DW1   = (bf*)(B0 + 6291456);          // [6,10)    4MB hi, read at dec1
  bf* DW2   = (bf*)(B0 + 10485760);         // [10,26)   16MB hi, read at dec2
  bf* WSP   = (bf*)(B0 + 27262976);         // [26,30)   4MB hi|lo
  bf* W2SP  = (bf*)(B0 + 31457280);         // [30,34)   4MB hi|lo
  bf* WTSP  = (bf*)(B0 + 35651584);         // [34,38)   4MB hi|lo, dead after W2 GEMM
  bf* ENC22 = (bf*)(B0 + 39845888);         // [38,46)   8MB hi, dead after xp
  float* XP = (float*)(B0 + 48234496);      // [46,62)   fp32, dead after y-combine
  bf* XP2   = (bf*)(B0 + 67108864);         // [64,80)   hi|lo (ENCB2 dead), dead after y-combine
  float* YF = (float*)(B0 + 83886080);      // [80,88)   dead after Horner-3
  bf* Y2    = (bf*)(B0 + 92274688);         // [88,96)   hi|lo, dead after Horner-1
  bf* H2    = (bf*)(B0 + 100663296);        // [96,98)
  bf* H22   = (bf*)(B0 + 102760448);        // [98,100)
  bf* P12   = (bf*)(B0 + 104857600);        // [100,104)
  float* PREDS = (float*)(B0 + 109051904);  // [104,112)
  bf* PREDS2 = (bf*)(B0);                   // [0,4)     written at ln (EW2 dead)
  bf* DBUF2 = (bf*)(B0 + 83886080);         // [80,88)   dec1 out (YF dead)
  float* DECO = (float*)(B0 + 33554432);    // [32,64)   dec2 out (WTSP/ENC22/XP dead)

  prep_kernel<<<256, 256, 0, stream>>>(x_enc, MEAN, STD, XNB);
  kfilt_kernel<<<8, 256, 0, stream>>>(mask_w, KF);
  cmat_kernel<<<512, 256, 0, stream>>>(KF, CM);

  // conv as MFMA GEMM (pure bf16 hi, NSEG=1): per nb [512,512] @ [8192,512]^T -> XIH scatter
  gemm_mfma<4, 4, 1><<<dim3(64, 4, 4), 256, 0, stream>>>(
      CM, 1024, 524288LL, 0LL, 0, XNB, 1024, 0LL, 0LL, 0,
      nullptr, 0, 0, nullptr, 0, 0, 0, nullptr, 0, 0, 0,
      XIH, 0, 0, 4194304LL, 0LL, 1, 512, 8192, 512, 0, 1, 0);

  // enc1: M=2048 N=1024 K=2048, NSEG=1, relu, hi out; swapg A-local
  splith_kernel<<<8192, 256, 0, stream>>>(enc_w1, WW);
  gemm_mfma<4, 2, 1><<<dim3(16, 16, 4), 256, 0, stream>>>(
      XIH, 2048, 4194304LL, 0LL, 0, WW, 2048, 2097152LL, 0LL, 0,
      enc_b1, 1024LL, 0LL, nullptr, 0, 0, 0, nullptr, 0, 0, 0,
      ENCB2, 1024, 0, 2097152LL, 0LL, 1, 2048, 1024, 2048, 1, 0, 1);

  // fused weight casts (XIH dead now): enc_w2|wxh|dec_w1|dec_w2 -> [0,26)
  splith4_kernel<<<13312, 256, 0, stream>>>(enc_w2, wxh, dec_w1, dec_w2, EW2);
  split_kernel<<<1024, 256, 0, stream>>>(whh, WSP, 9);
  tsplit_kernel<<<dim3(8, 8, 4), 256, 0, stream>>>(whh, WTSP);

  // enc2: M=2048 N=512 K=1024, NSEG=1, hi out; swapg
  gemm_mfma<4, 2, 1><<<dim3(16, 8, 4), 256, 0, stream>>>(
      ENCB2, 1024, 2097152LL, 0LL, 0, EW2, 1024, 524288LL, 0LL, 0,
      enc_b2, 512LL, 0LL, nullptr, 0, 0, 0, nullptr, 0, 0, 0,
      ENC22, 512, 0, 1048576LL, 0LL, 1, 2048, 512, 1024, 0, 0, 1);

  // xp = enc2 @ wxh^T: NSEG=1; fp32 out + XP2 hi|lo-concat (mode 2); swapg
  gemm_mfma<4, 2, 1><<<dim3(16, 8, 4), 256, 0, stream>>>(
      ENC22, 512, 1048576LL, 0LL, 0, WXH2, 512, 262144LL, 0LL, 0,
      nullptr, 0, 0, nullptr, 0, 0, 0, XP, 512, 1048576LL, 0LL,
      XP2, 0, 0, 2097152LL, 0LL, 1, 2048, 512, 512, 0, 2, 1);

  // W2 = W @ W (NSEG=3) -> split-out W2SP
  gemm_mfma<2, 2, 3><<<dim3(8, 8, 4), 256, 0, stream>>>(
      WSP, 1024, 524288LL, 0LL, 512, WTSP, 1024, 524288LL, 0LL, 512,
      nullptr, 0, 0, nullptr, 0, 0, 0, nullptr, 0, 0, 0,
      W2SP, 1024, 512, 524288LL, 0LL, 1, 512, 512, 512, 0, 0, 0);

  // y_j = xp_{2j} @ W^T + xp_{2j+1}   (z1 = j, z2 = nb, 16 total), NSEG=3
  gemm_mfma<2, 2, 3><<<dim3(8, 4, 16), 256, 0, stream>>>(
      XP2, 8192, 1024LL, 2097152LL, 4096, WSP, 1024, 0LL, 524288LL, 512,
      nullptr, 0, 0, XP + 512, 4096, 1024LL, 1048576LL,
      YF, 512, 524288LL, 131072LL,
      Y2, 1024, 512, 1048576LL, 262144LL, 4, 256, 512, 512, 0, 0, 0);

  // Horner with W2 (NSEG=3)
  gemm_mfma<2, 2, 3><<<dim3(8, 4, 4), 256, 0, stream>>>(
      Y2, 1024, 0LL, 262144LL, 512, W2SP, 1024, 0LL, 524288LL, 512,
      nullptr, 0, 0, YF + 524288, 512, 0LL, 131072LL, nullptr, 0, 0, 0,
      H2, 1024, 512, 0LL, 262144LL, 4, 256, 512, 512, 0, 0, 0);
  gemm_mfma<2, 2, 3><<<dim3(8, 4, 4), 256, 0, stream>>>(
      H2, 1024, 0LL, 262144LL, 512, W2SP, 1024, 0LL, 524288LL, 512,
      nullptr, 0, 0, YF + 1048576, 512, 0LL, 131072LL, nullptr, 0, 0, 0,
      H22, 1024, 512, 0LL, 262144LL, 4, 256, 512, 512, 0, 0, 0);
  gemm_mfma<2, 2, 3><<<dim3(8, 4, 4), 256, 0, stream>>>(
      H22, 1024, 0LL, 262144LL, 512, W2SP, 1024, 0LL, 524288LL, 512,
      nullptr, 0, 0, YF + 1572864, 512, 0LL, 131072LL, nullptr, 0, 0, 0,
      H2, 1024, 512, 0LL, 262144LL, 4, 256, 512, 512, 0, 0, 0);

  // free-run A: p1 = h@W^T (z1=0), p2 = h@W2^T (z1=1), NSEG=3
  gemm_mfma<2, 2, 3><<<dim3(8, 4, 8), 256, 0, stream>>>(
      H2, 1024, 0LL, 262144LL, 512, WSP, 1024, 2097152LL, 524288LL, 512,
      nullptr, 0, 0, nullptr, 0, 0, 0, PREDS, 2048, 512LL, 524288LL,
      P12, 1024, 512, 1048576LL, 262144LL, 4, 256, 512, 512, 0, 0, 0);
  // free-run B: p3 = p1@W2^T, p4 = p2@W2^T, NSEG=3
  gemm_mfma<2, 2, 3><<<dim3(8, 4, 8), 256, 0, stream>>>(
      P12, 1024, 1048576LL, 262144LL, 512, W2SP, 1024, 0LL, 524288LL, 512,
      nullptr, 0, 0, nullptr, 0, 0, 0, PREDS + 1024, 2048, 512LL, 524288LL,
      nullptr, 0, 0, 0LL, 0LL, 4, 256, 512, 512, 0, 0, 0);

  ln_kernel<<<4096, 256, 0, stream>>>(PREDS, ln_g, ln_b, PREDS2);

  // dec1: M=1024 N=1024 K=512, NSEG=1, relu, hi out
  gemm_mfma<4, 2, 1><<<dim3(16, 8, 4), 256, 0, stream>>>(
      PREDS2, 512, 524288LL, 0LL, 0, DW1, 512, 524288LL, 0LL, 0,
      dec_b1, 1024LL, 0LL, nullptr, 0, 0, 0, nullptr, 0, 0, 0,
      DBUF2, 1024, 0, 1048576LL, 0LL, 1, 1024, 1024, 512, 1, 0, 0);
  // dec2: M=1024 N=2048 K=1024, NSEG=1, fp32 out
  gemm_mfma<4, 2, 1><<<dim3(32, 8, 4), 256, 0, stream>>>(
      DBUF2, 1024, 1048576LL, 0LL, 0, DW2, 1024, 2097152LL, 0LL, 0,
      dec_b2, 2048LL, 0LL, nullptr, 0, 0, 0, DECO, 2048, 2097152LL, 0LL,
      nullptr, 0, 0, 0LL, 0LL, 1, 1024, 2048, 1024, 0, 0, 0);

  final_kernel<<<2048, 256, 0, stream>>>(DECO, MEAN, STD, out);
}